// Round 6
// baseline (682.730 us; speedup 1.0000x reference)
//
#include <hip/hip_runtime.h>

#define NV0 30000
#define NE0 90000
#define H0 (2*NE0)      // 180000
#define NV1 (NV0+NE0)   // 120000
#define NE1 (3*NE0)     // 270000
#define H1 (2*NE1)      // 540000
#define DF 32
#define DH 128

typedef unsigned short bf16_t;
typedef unsigned int u32;
typedef __attribute__((ext_vector_type(8))) short short8;
typedef __attribute__((ext_vector_type(4))) float f32x4;

__device__ __forceinline__ float bf2f(bf16_t b) { return __uint_as_float(((u32)b) << 16); }
__device__ __forceinline__ bf16_t f2bf(float f) {
  u32 u = __float_as_uint(f);
  return (bf16_t)((u + 0x7fffu + ((u >> 16) & 1u)) >> 16);
}
__device__ __forceinline__ u32 pack2bf(float a, float b) {
  return (u32)f2bf(a) | ((u32)f2bf(b) << 16);
}
__device__ __forceinline__ float load_f(const void* p, long i, int isf32) {
  return isf32 ? ((const float*)p)[i] : bf2f(((const bf16_t*)p)[i]);
}
__device__ __forceinline__ void store_out(void* p, long i, float v, int isf32) {
  if (isf32) ((float*)p)[i] = v;
  else ((bf16_t*)p)[i] = f2bf(v);
}

// Compile-time ordering fence for cross-lane LDS RAW/WAR hazards within a wave.
// HW processes a wave's DS ops in issue order; this stops the COMPILER from
// reordering ds_read/ds_write across the point. NOTE: register values flow
// across freely — the W-prefetch chain exploits that.
__device__ __forceinline__ void lds_fence() {
  asm volatile("" ::: "memory");
  __builtin_amdgcn_sched_barrier(0);
}

// quad (4-lane group) broadcasts via DPP — VALU, replaces ds_bpermute __shfl
__device__ __forceinline__ float qb0(float x){ return __int_as_float(__builtin_amdgcn_mov_dpp(__float_as_int(x), 0x00, 0xf, 0xf, true)); }
__device__ __forceinline__ float qb1(float x){ return __int_as_float(__builtin_amdgcn_mov_dpp(__float_as_int(x), 0x55, 0xf, 0xf, true)); }
__device__ __forceinline__ float qb2(float x){ return __int_as_float(__builtin_amdgcn_mov_dpp(__float_as_int(x), 0xAA, 0xf, 0xf, true)); }
__device__ __forceinline__ float qb3(float x){ return __int_as_float(__builtin_amdgcn_mov_dpp(__float_as_int(x), 0xFF, 0xf, 0xf, true)); }

struct F3 { float x, y, z; };
__device__ __forceinline__ F3 mkf3(float x, float y, float z){ F3 r; r.x=x; r.y=y; r.z=z; return r; }
__device__ __forceinline__ F3 f3sub(F3 a, F3 b){ return mkf3(a.x-b.x, a.y-b.y, a.z-b.z); }
__device__ __forceinline__ F3 f3add(F3 a, F3 b){ return mkf3(a.x+b.x, a.y+b.y, a.z+b.z); }
__device__ __forceinline__ float f3dot(F3 a, F3 b){ return a.x*b.x + a.y*b.y + a.z*b.z; }
__device__ __forceinline__ F3 f3crs(F3 a, F3 b){
  return mkf3(a.y*b.z - a.z*b.y, a.z*b.x - a.x*b.z, a.x*b.y - a.y*b.x);
}
__device__ __forceinline__ F3 f3nrm(F3 a){
  float r = rsqrtf(f3dot(a,a));
  return mkf3(a.x*r, a.y*r, a.z*r);
}

// ---- dtype detection
__global__ __launch_bounds__(256) void detect_kernel(const u32* __restrict__ fvw,
                                                     int* __restrict__ flag) {
  __shared__ int cnt;
  if (threadIdx.x == 0) cnt = 0;
  __syncthreads();
  int c = 0;
  #pragma unroll
  for (int j = 0; j < 2; ++j) {
    u32 w = fvw[threadIdx.x * 2 + j];
    u32 e = (w >> 7) & 0xffu;
    if (e > 140u) c++;
  }
  if (c) atomicAdd(&cnt, c);
  __syncthreads();
  if (threadIdx.x == 0) *flag = (cnt > 8) ? 1 : 0;
}

// biases: flagged dtype -> fp32
__global__ __launch_bounds__(256) void cvt_weights_kernel(const void* __restrict__ src,
                                                          float* __restrict__ dst, int n,
                                                          const int* __restrict__ flag) {
  int t = blockIdx.x * 256 + threadIdx.x;
  if (t >= n) return;
  dst[t] = load_f(src, t, *flag);
}

// Transposed bf16 weights for MFMA B-operand (layout [subnet][n][k], k contiguous).
__global__ __launch_bounds__(256) void pt_win_kernel(const void* __restrict__ W_in,
                                                     bf16_t* __restrict__ dst,
                                                     const int* __restrict__ flag) {
  int t = blockIdx.x * 256 + threadIdx.x;
  if (t >= 4 * DH * DH) return;
  int s = t >> 14, n = (t >> 7) & 127, k = t & 127;
  float v = (k >= 3) ? load_f(W_in, (long)s * (125 * DH) + (k - 3) * DH + n, *flag) : 0.f;
  dst[t] = f2bf(v);
}
__global__ __launch_bounds__(256) void pt_wh_kernel(const void* __restrict__ W_h,
                                                    bf16_t* __restrict__ dst,
                                                    const int* __restrict__ flag) {
  int t = blockIdx.x * 256 + threadIdx.x;
  if (t >= 4 * DH * DH) return;
  int s = t >> 14, n = (t >> 7) & 127, k = t & 127;
  dst[t] = f2bf(load_f(W_h, (long)s * (DH * DH) + k * DH + n, *flag));
}
__global__ __launch_bounds__(256) void pt_wo_kernel(const void* __restrict__ W_out,
                                                    bf16_t* __restrict__ dst,
                                                    const int* __restrict__ flag) {
  int t = blockIdx.x * 256 + threadIdx.x;
  if (t >= 4 * 32 * DH) return;
  int s = t >> 12, n = (t >> 7) & 31, k = t & 127;
  dst[t] = f2bf(load_f(W_out, (long)s * (DH * 32) + k * 32 + n, *flag));
}

// output 0: exact passthrough of fv positions
__global__ __launch_bounds__(256) void cvt_out0_kernel(const void* __restrict__ fv,
                                                       void* __restrict__ out,
                                                       const int* __restrict__ flag) {
  int t = blockIdx.x * 256 + threadIdx.x;
  if (t >= NV0 * 3) return;
  int v = t / 3, c = t - v * 3;
  if (*flag) ((float*)out)[t] = ((const float*)fv)[v * DF + c];
  else ((bf16_t*)out)[t] = ((const bf16_t*)fv)[v * DF + c];
}

#define XST 136   // LDS row stride (bf16 elems): 272B

__device__ __forceinline__ f32x4 mfma16(short8 a, short8 b, f32x4 c) {
  return __builtin_amdgcn_mfma_f32_16x16x32_bf16(a, b, c, 0, 0, 0);
}

// W prefetch batch: the 4 kq-fragments of the first row-block's w0 side (16 VGPR).
typedef struct { short8 w[4]; } W4;
__device__ __forceinline__ W4 loadW4(const bf16_t* __restrict__ Wt, int arow, int koff) {
  W4 r;
  #pragma unroll
  for (int kq = 0; kq < 4; ++kq)
    r.w[kq] = *(const short8*)(Wt + arow * DH + kq * 32 + koff);
  return r;
}

// One 128->128 layer IN-PLACE, M=32 rows per wave. Uses a pre-issued W batch
// (wpre, loaded in the PREVIOUS phase) and issues the NEXT phase's batch right
// after its own af reads — that load's latency retires under this layer's
// MFMA/store loop instead of serializing at the next phase boundary.
__device__ __forceinline__ W4 mlp_layer2(
    short* buf,
    const bf16_t* __restrict__ Wt, const float* __restrict__ bias,
    W4 wpre, const bf16_t* __restrict__ Wtnext,
    int m0, int arow, int koff, int rrow)
{
  lds_fence();   // order af reads after previous phase's cross-lane LDS writes
  short8 af[2][4];
  #pragma unroll
  for (int mt = 0; mt < 2; ++mt)
    #pragma unroll
    for (int kq = 0; kq < 4; ++kq)
      af[mt][kq] = *(const short8*)(buf + (m0 + mt * 16 + arow) * XST + kq * 32 + koff);
  W4 wnext = loadW4(Wtnext, arow, koff);   // cross-phase prefetch (register carry)
  lds_fence();   // ALL tile reads issued before ANY in-place store (cross-lane WAR)
  #pragma unroll
  for (int ntl = 0; ntl < 8; ntl += 2) {
    f32x4 a00 = {0.f,0.f,0.f,0.f}, a01 = {0.f,0.f,0.f,0.f};
    f32x4 a10 = {0.f,0.f,0.f,0.f}, a11 = {0.f,0.f,0.f,0.f};
    #pragma unroll
    for (int kq = 0; kq < 4; ++kq) {
      short8 w0 = (ntl == 0) ? wpre.w[kq]
                 : *(const short8*)(Wt + (ntl * 16 + arow) * DH + kq * 32 + koff);
      short8 w1 = *(const short8*)(Wt + ((ntl + 1) * 16 + arow) * DH + kq * 32 + koff);
      a00 = mfma16(af[0][kq], w0, a00);
      a01 = mfma16(af[0][kq], w1, a01);
      a10 = mfma16(af[1][kq], w0, a10);
      a11 = mfma16(af[1][kq], w1, a11);
    }
    int c0 = ntl * 16 + arow, c1 = c0 + 16;
    float bb0 = bias[c0], bb1 = bias[c1];
    #pragma unroll
    for (int r = 0; r < 4; ++r) {
      int rmA = m0 + rrow + r, rmB = m0 + 16 + rrow + r;
      buf[rmA * XST + c0] = (short)f2bf(fmaxf(a00[r] + bb0, 0.f));
      buf[rmA * XST + c1] = (short)f2bf(fmaxf(a01[r] + bb1, 0.f));
      buf[rmB * XST + c0] = (short)f2bf(fmaxf(a10[r] + bb0, 0.f));
      buf[rmB * XST + c1] = (short)f2bf(fmaxf(a11[r] + bb1, 0.f));
    }
  }
  lds_fence();   // order this layer's writes before next phase's reads
  return wnext;
}

// frame + merged store for one flap row (math identical to round-5 kernel;
// quad-broadcasts via DPP instead of ds_bpermute __shfl).
template<int ISF32>
__device__ __forceinline__ void frame_store(const float4* xf, const uint4* xr,
                                            int m, int v, short* Xl, float* LFl) {
  u32 w[16];
  float px, py, pz;
  if (ISF32) {
    px = xf[0].x; py = xf[0].y; pz = xf[0].z;
    #pragma unroll
    for (int j = 0; j < 8; ++j) {
      w[2 * j]     = pack2bf(xf[j].x, xf[j].y);
      w[2 * j + 1] = pack2bf(xf[j].z, xf[j].w);
    }
  } else {
    #pragma unroll
    for (int j = 0; j < 4; ++j) {
      w[4 * j + 0] = xr[j].x; w[4 * j + 1] = xr[j].y;
      w[4 * j + 2] = xr[j].z; w[4 * j + 3] = xr[j].w;
    }
    px = bf2f((bf16_t)(w[0] & 0xffff));
    py = bf2f((bf16_t)(w[0] >> 16));
    pz = bf2f((bf16_t)(w[1] & 0xffff));
  }
  F3 p0 = mkf3(qb0(px), qb0(py), qb0(pz));
  F3 p1 = mkf3(qb1(px), qb1(py), qb1(pz));
  F3 p2 = mkf3(qb2(px), qb2(py), qb2(pz));
  F3 p3 = mkf3(qb3(px), qb3(py), qb3(pz));
  F3 e1  = f3sub(p1, p0);
  F3 B1  = f3nrm(e1);
  F3 fn0 = f3nrm(f3crs(e1, f3sub(p2, p0)));
  F3 fn1 = f3nrm(f3crs(f3sub(p0, p1), f3sub(p3, p1)));
  F3 B3  = f3nrm(f3add(fn0, fn1));
  F3 B2  = f3crs(B3, B1);
  if (v == 0) {
    float* lf = LFl + m * 9;
    lf[0] = B1.x; lf[1] = B1.y; lf[2] = B1.z;
    lf[3] = B2.x; lf[4] = B2.y; lf[5] = B2.z;
    lf[6] = B3.x; lf[7] = B3.y; lf[8] = B3.z;
    // v0 pos channels (k 0..2) hit zero rows of Wt1 -> keep raw, no need to clear
  } else {
    // channels v*32 + {0,1,2} = local coords of (p_v - p0); channel v*32+3 kept original
    F3 d = f3sub(mkf3(px, py, pz), p0);
    w[0] = pack2bf(f3dot(d, B1), f3dot(d, B2));
    w[1] = (w[1] & 0xffff0000u) | (u32)f2bf(f3dot(d, B3));
  }
  uint4* xrow = (uint4*)(Xl + m * XST + v * 32);   // 272B row stride: 16B-aligned
  #pragma unroll
  for (int j = 0; j < 4; ++j)
    xrow[j] = make_uint4(w[4 * j], w[4 * j + 1], w[4 * j + 2], w[4 * j + 3]);
}

// Fused per-pass kernel. 128 flaps/block, M=32 per wave (wave wv owns rows
// [32wv, 32wv+32) end-to-end — strictly wave-local, barrier-free).
// IN-PLACE layers: single X buffer -> LDS ~40KB -> 4 blocks/CU (16 waves/CU).
// Deep per-wave pipelining: both gather halves issued up-front; W prefetch
// chained across every phase boundary. XCD-chunked bijective block swizzle.
template<int MODE, int RAW>
__global__ __launch_bounds__(256, 4) void mlp3_kernel(
    const void* __restrict__ fvin, const int* __restrict__ hfIdx, int nH,
    const bf16_t* __restrict__ Wt1, const bf16_t* __restrict__ Wt2,
    const bf16_t* __restrict__ Wt3,
    const float* __restrict__ b1, const float* __restrict__ b2,
    const float* __restrict__ b3,
    float* __restrict__ outp, float* __restrict__ dofp,
    const int* __restrict__ flag)
{
  __shared__ __align__(16) short Xl[128 * XST];  // X tile; later H; later Y (fp32, stride 68, row-own)
  __shared__ float LFl[128 * 9];
  __shared__ int   idxl[128];                    // center vertex per flap

  const int t = threadIdx.x;
  const int lane = t & 63;
  const int m0 = (t >> 6) * 32;
  const int arow = lane & 15;
  const int koff = (lane >> 4) * 8;
  const int rrow = (lane >> 4) * 4;
  const int isf32 = RAW ? *flag : 1;

  // bijective XCD-chunked swizzle: blocks on one XCD get a contiguous flap range
  const int nwg = gridDim.x;
  const int q = nwg >> 3, r = nwg & 7;
  const int xcd = blockIdx.x & 7;
  const int loc = blockIdx.x >> 3;
  const int bswz = (xcd < r ? xcd * (q + 1) : r * (q + 1) + (xcd - r) * q) + loc;
  const long h0 = (long)bswz * 128;

  // layer-1 W prefetch issues first: retires under the whole gather phase
  W4 wp = loadW4(Wt1, arow, koff);

  // ---- phase 1: gather (both halves' loads issued before any frame math)
  {
    const int mA = m0 + (lane >> 2), mB = mA + 16;
    const int v = lane & 3;
    const long hA = h0 + mA, hB = h0 + mB;
    int vidA = (hA < nH) ? hfIdx[hA * 4 + v] : 0;
    int vidB = (hB < nH) ? hfIdx[hB * 4 + v] : 0;
    if (v == 0) { idxl[mA] = vidA; idxl[mB] = vidB; }
    if (RAW && !isf32) {
      uint4 rA[4], rB[4];
      const uint4* sA = (const uint4*)((const bf16_t*)fvin + (size_t)vidA * DF);
      const uint4* sB = (const uint4*)((const bf16_t*)fvin + (size_t)vidB * DF);
      #pragma unroll
      for (int j = 0; j < 4; ++j) rA[j] = sA[j];
      #pragma unroll
      for (int j = 0; j < 4; ++j) rB[j] = sB[j];
      frame_store<0>(nullptr, rA, mA, v, Xl, LFl);
      frame_store<0>(nullptr, rB, mB, v, Xl, LFl);
    } else {
      float4 xA[8], xB[8];
      const float4* sA = (const float4*)((const float*)fvin + (size_t)vidA * DF);
      const float4* sB = (const float4*)((const float*)fvin + (size_t)vidB * DF);
      #pragma unroll
      for (int j = 0; j < 8; ++j) xA[j] = sA[j];
      #pragma unroll
      for (int j = 0; j < 8; ++j) xB[j] = sB[j];
      frame_store<1>(xA, nullptr, mA, v, Xl, LFl);
      frame_store<1>(xB, nullptr, mB, v, Xl, LFl);
    }
  }

  // ======== LAYER 1 / LAYER 2 (wave-local, in-place, W-prefetch chained) ========
  wp = mlp_layer2(Xl, Wt1, b1, wp, Wt2, m0, arow, koff, rrow);
  wp = mlp_layer2(Xl, Wt2, b2, wp, Wt3, m0, arow, koff, rrow);

  // ======== LAYER 3: Y = H2 @ W3 + b3 (N=32, no relu); Y fp32 into row-own Xl storage ========
  {
    lds_fence();   // order af reads after layer-2's cross-lane Xl writes
    short8 af[2][4];
    #pragma unroll
    for (int mt = 0; mt < 2; ++mt)
      #pragma unroll
      for (int kq = 0; kq < 4; ++kq)
        af[mt][kq] = *(const short8*)(Xl + (m0 + mt * 16 + arow) * XST + kq * 32 + koff);
    f32x4 a00 = {0.f,0.f,0.f,0.f}, a01 = {0.f,0.f,0.f,0.f};
    f32x4 a10 = {0.f,0.f,0.f,0.f}, a11 = {0.f,0.f,0.f,0.f};
    #pragma unroll
    for (int kq = 0; kq < 4; ++kq) {
      short8 w0 = wp.w[kq];
      short8 w1 = *(const short8*)(Wt3 + (16 + arow) * DH + kq * 32 + koff);
      a00 = mfma16(af[0][kq], w0, a00);
      a01 = mfma16(af[0][kq], w1, a01);
      a10 = mfma16(af[1][kq], w0, a10);
      a11 = mfma16(af[1][kq], w1, a11);
    }
    lds_fence();   // af reads ordered before aliasing Yf writes
    float* Yf = (float*)Xl;
    float bb0 = b3[arow], bb1 = b3[16 + arow];
    #pragma unroll
    for (int r = 0; r < 4; ++r) {
      int rmA = m0 + rrow + r, rmB = m0 + 16 + rrow + r;
      Yf[rmA * 68 + arow]      = a00[r] + bb0;   // row rm's Y lives in row rm's Xl bytes
      Yf[rmA * 68 + 16 + arow] = a01[r] + bb1;
      Yf[rmB * 68 + arow]      = a10[r] + bb0;
      Yf[rmB * 68 + 16 + arow] = a11[r] + bb1;
    }
  }
  lds_fence();     // Yf writes ordered before epilogue's cross-lane reads

  // ======== epilogue: local2global + pool (wave-own 32 rows) ========
  float* Yf = (float*)Xl;
  #pragma unroll
  for (int i = 0; i < 16; ++i) {
    int row = m0 + i * 2 + (lane >> 5);
    long h = h0 + row;
    int ch = lane & 31;
    float val = 0.f;
    if (h < nH) {
      val = Yf[row * 68 + ch];
      if (ch < 3) {
        float y0 = Yf[row * 68 + 0], y1 = Yf[row * 68 + 1], y2 = Yf[row * 68 + 2];
        val = y0 * LFl[row * 9 + ch] + y1 * LFl[row * 9 + 3 + ch] + y2 * LFl[row * 9 + 6 + ch];
      }
    }
    if (MODE == 0) {
      if (h < nH) {
        atomicAdd(&outp[(size_t)idxl[row] * DF + ch], val);
        if (ch == 0) atomicAdd(&dofp[idxl[row]], 1.f);
      }
    } else {
      // half-edge pair (2e,2e+1) sits on lanes l / l+32 of this iteration:
      // combine in-wave -> plain store, no atomics, no zero-init of the odd buffer.
      float sum = val + __shfl_xor(val, 32);
      if (h < nH && lane < 32) {
        if (MODE == 1) outp[(size_t)(h >> 1) * DF + ch] = 0.5f * sum;
        else if (ch < 3) outp[(size_t)(h >> 1) * 3 + ch] = 0.5f * sum;
      }
    }
  }
}

// ---- finalize kernels ----
template<int RAW>
__global__ __launch_bounds__(256) void finalize_even_kernel(
    float* buf, const float* __restrict__ dof,
    const void* __restrict__ prevraw, const float* __restrict__ prevf,
    void* __restrict__ out, int outbase, const int* __restrict__ flag, int nV) {
  int t = blockIdx.x * 256 + threadIdx.x;
  if (t >= nV * DF) return;
  int v = t >> 5, c = t & 31;
  float val = buf[t] / fmaxf(dof[v], 1.0f);
  if (c < 3) {
    float pp = RAW ? load_f(prevraw, (long)v * DF + c, *flag) : prevf[(long)v * DF + c];
    val += pp;
    store_out(out, (long)outbase + (long)v * 3 + c, val, *flag);
  }
  buf[t] = val;
}

__global__ __launch_bounds__(256) void finalize_odd_full_kernel(
    float* oddbuf, const int* __restrict__ hfIdx,
    const float* fveven, void* __restrict__ out, int outbase,
    const int* __restrict__ flag, int nE, int nVeven) {
  int t = blockIdx.x * 256 + threadIdx.x;
  if (t >= nE * DF) return;
  int e = t >> 5, c = t & 31;
  float val = oddbuf[t];
  if (c < 3) {
    int a0 = hfIdx[(size_t)(2 * e) * 4 + 0];
    int a1 = hfIdx[(size_t)(2 * e) * 4 + 1];
    int b0 = hfIdx[(size_t)(2 * e + 1) * 4 + 0];
    int b1 = hfIdx[(size_t)(2 * e + 1) * 4 + 1];
    val += 0.25f * (fveven[(size_t)a0 * DF + c] + fveven[(size_t)a1 * DF + c] +
                    fveven[(size_t)b0 * DF + c] + fveven[(size_t)b1 * DF + c]);
    store_out(out, (long)outbase + (long)(nVeven + e) * 3 + c, val, *flag);
  }
  oddbuf[t] = val;
}

__global__ __launch_bounds__(256) void finalize_odd_pos_kernel(
    const float* __restrict__ odd3, const int* __restrict__ hfIdx,
    const float* __restrict__ fveven, void* __restrict__ out, int outbase,
    const int* __restrict__ flag, int nE, int nVeven) {
  int t = blockIdx.x * 256 + threadIdx.x;
  if (t >= nE * 3) return;
  int e = t / 3, c = t - e * 3;
  int a0 = hfIdx[(size_t)(2 * e) * 4 + 0];
  int a1 = hfIdx[(size_t)(2 * e) * 4 + 1];
  int b0 = hfIdx[(size_t)(2 * e + 1) * 4 + 0];
  int b1 = hfIdx[(size_t)(2 * e + 1) * 4 + 1];
  float val = odd3[t] + 0.25f * (fveven[(size_t)a0 * DF + c] + fveven[(size_t)a1 * DF + c] +
                                 fveven[(size_t)b0 * DF + c] + fveven[(size_t)b1 * DF + c]);
  store_out(out, (long)outbase + (long)(nVeven + e) * 3 + c, val, *flag);
}

extern "C" void kernel_launch(void* const* d_in, const int* in_sizes, int n_in,
                              void* d_out, int out_size, void* d_ws, size_t ws_size,
                              hipStream_t stream) {
  const void* fv    = d_in[0];
  const void* W_in  = d_in[1];
  const void* b_in  = d_in[2];
  const void* W_h   = d_in[3];
  const void* b_h   = d_in[4];
  const void* W_out = d_in[5];
  const void* b_out = d_in[6];
  const int* hf0 = (const int*)d_in[7];
  const int* hf1 = (const int*)d_in[8];
  (void)in_sizes; (void)n_in; (void)out_size;

  // workspace (~29.8 MiB)
  float* fv1   = (float*)d_ws;            // 3,840,000 (120000x32)
  float* fvup2 = fv1   + 3840000;         // 3,840,000
  float* dof   = fvup2 + 3840000;         // 120,000
  float* bif   = dof   + 120000;          // 512
  float* bhf   = bif   + 512;             // 512
  float* bof   = bhf   + 512;             // 128
  int*   flag  = (int*)(bof + 128);       // 4 ints (1 used)
  bf16_t* Wti  = (bf16_t*)(flag + 4);     // 4x128x128
  bf16_t* Wth  = Wti + 65536;             // 4x128x128
  bf16_t* Wto  = Wth + 65536;             // 4x32x128
  const size_t needed = ((size_t)3840000 * 2 + 120000 + 512 * 2 + 128 + 4) * 4
                      + (65536 * 2 + 16384) * 2;
  if (ws_size < needed) return;

  float* odd_acc0 = fv1 + (size_t)NV0 * DF;  // level-0 odd region (90000x32)

  // ---- dtype detect + weight staging
  detect_kernel<<<1, 256, 0, stream>>>((const u32*)fv, flag);
  pt_win_kernel<<<256, 256, 0, stream>>>(W_in, Wti, flag);
  pt_wh_kernel<<<256, 256, 0, stream>>>(W_h, Wth, flag);
  pt_wo_kernel<<<64, 256, 0, stream>>>(W_out, Wto, flag);
  cvt_weights_kernel<<<2, 256, 0, stream>>>(b_in, bif, 512, flag);
  cvt_weights_kernel<<<2, 256, 0, stream>>>(b_h, bhf, 512, flag);
  cvt_weights_kernel<<<1, 256, 0, stream>>>(b_out, bof, 128, flag);
  cvt_out0_kernel<<<(NV0 * 3 + 255) / 256, 256, 0, stream>>>(fv, d_out, flag);

  const int G0 = (H0 + 127) / 128, G1 = (H1 + 127) / 128;

  // ================= level 0 =================
  hipMemsetAsync(fv1, 0, (size_t)NV0 * DF * 4, stream);
  hipMemsetAsync(dof, 0, (size_t)NV0 * 4, stream);
  mlp3_kernel<0, 1><<<G0, 256, 0, stream>>>(fv, hf0, H0,
      Wti + 0 * 16384, Wth + 0 * 16384, Wto + 0 * 4096,
      bif + 0 * DH, bhf + 0 * DH, bof + 0 * DF, fv1, dof, flag);
  finalize_even_kernel<1><<<(NV0 * DF + 255) / 256, 256, 0, stream>>>(
      fv1, dof, fv, nullptr, d_out, 90000, flag, NV0);
  // odd pass fully overwrites odd_acc0 (pair-combined plain stores) -> no memset
  mlp3_kernel<1, 0><<<G0, 256, 0, stream>>>(fv1, hf0, H0,
      Wti + 1 * 16384, Wth + 1 * 16384, Wto + 1 * 4096,
      bif + 1 * DH, bhf + 1 * DH, bof + 1 * DF, odd_acc0, nullptr, flag);
  finalize_odd_full_kernel<<<(NE0 * DF + 255) / 256, 256, 0, stream>>>(
      odd_acc0, hf0, fv1, d_out, 90000, flag, NE0, NV0);

  // ================= level 1 =================
  hipMemsetAsync(fvup2, 0, (size_t)NV1 * DF * 4, stream);
  hipMemsetAsync(dof, 0, (size_t)NV1 * 4, stream);
  mlp3_kernel<0, 0><<<G1, 256, 0, stream>>>(fv1, hf1, H1,
      Wti + 2 * 16384, Wth + 2 * 16384, Wto + 2 * 4096,
      bif + 2 * DH, bhf + 2 * DH, bof + 2 * DF, fvup2, dof, flag);
  finalize_even_kernel<0><<<(NV1 * DF + 255) / 256, 256, 0, stream>>>(
      fvup2, dof, nullptr, fv1, d_out, 450000, flag, NV1);
  // odd3 region fully overwritten by MODE 2 stores -> no memset
  mlp3_kernel<2, 0><<<G1, 256, 0, stream>>>(fvup2, hf1, H1,
      Wti + 3 * 16384, Wth + 3 * 16384, Wto + 3 * 4096,
      bif + 3 * DH, bhf + 3 * DH, bof + 3 * DF, fv1, nullptr, flag);
  finalize_odd_pos_kernel<<<(NE1 * 3 + 255) / 256, 256, 0, stream>>>(
      fv1, hf1, fvup2, d_out, 450000, flag, NE1, NV1);
}

// Round 7
// 638.961 us; speedup vs baseline: 1.0685x; 1.0685x over previous
//
#include <hip/hip_runtime.h>

#define NV0 30000
#define NE0 90000
#define H0 (2*NE0)      // 180000
#define NV1 (NV0+NE0)   // 120000
#define NE1 (3*NE0)     // 270000
#define H1 (2*NE1)      // 540000
#define DF 32
#define DH 128

typedef unsigned short bf16_t;
typedef unsigned int u32;
typedef __attribute__((ext_vector_type(8))) short short8;
typedef __attribute__((ext_vector_type(4))) float f32x4;

__device__ __forceinline__ float bf2f(bf16_t b) { return __uint_as_float(((u32)b) << 16); }
__device__ __forceinline__ bf16_t f2bf(float f) {
  u32 u = __float_as_uint(f);
  return (bf16_t)((u + 0x7fffu + ((u >> 16) & 1u)) >> 16);
}
__device__ __forceinline__ u32 pack2bf(float a, float b) {
  return (u32)f2bf(a) | ((u32)f2bf(b) << 16);
}
__device__ __forceinline__ float load_f(const void* p, long i, int isf32) {
  return isf32 ? ((const float*)p)[i] : bf2f(((const bf16_t*)p)[i]);
}
__device__ __forceinline__ void store_out(void* p, long i, float v, int isf32) {
  if (isf32) ((float*)p)[i] = v;
  else ((bf16_t*)p)[i] = f2bf(v);
}

// Compile-time ordering fence for cross-lane LDS RAW/WAR hazards within a wave.
// HW processes a wave's DS ops in issue order; we only need the COMPILER not to
// reorder ds_read/ds_write across this point. A wavefront-scope fence is
// ModRef-everything for alias analysis (orders all memory ops in IR/MIR) but
// legalizes to at most an lgkmcnt wait — crucially NO vmcnt(0) drain, unlike an
// unknown-memory asm clobber (which cost ~9 full VMEM drains per wave, the
// round-5 serializer).
__device__ __forceinline__ void lds_fence() {
  __builtin_amdgcn_fence(__ATOMIC_ACQ_REL, "wavefront");
  __builtin_amdgcn_sched_barrier(0);
}

struct F3 { float x, y, z; };
__device__ __forceinline__ F3 mkf3(float x, float y, float z){ F3 r; r.x=x; r.y=y; r.z=z; return r; }
__device__ __forceinline__ F3 f3sub(F3 a, F3 b){ return mkf3(a.x-b.x, a.y-b.y, a.z-b.z); }
__device__ __forceinline__ F3 f3add(F3 a, F3 b){ return mkf3(a.x+b.x, a.y+b.y, a.z+b.z); }
__device__ __forceinline__ float f3dot(F3 a, F3 b){ return a.x*b.x + a.y*b.y + a.z*b.z; }
__device__ __forceinline__ F3 f3crs(F3 a, F3 b){
  return mkf3(a.y*b.z - a.z*b.y, a.z*b.x - a.x*b.z, a.x*b.y - a.y*b.x);
}
__device__ __forceinline__ F3 f3nrm(F3 a){
  float r = rsqrtf(f3dot(a,a));
  return mkf3(a.x*r, a.y*r, a.z*r);
}

// ---- dtype detection
__global__ __launch_bounds__(256) void detect_kernel(const u32* __restrict__ fvw,
                                                     int* __restrict__ flag) {
  __shared__ int cnt;
  if (threadIdx.x == 0) cnt = 0;
  __syncthreads();
  int c = 0;
  #pragma unroll
  for (int j = 0; j < 2; ++j) {
    u32 w = fvw[threadIdx.x * 2 + j];
    u32 e = (w >> 7) & 0xffu;
    if (e > 140u) c++;
  }
  if (c) atomicAdd(&cnt, c);
  __syncthreads();
  if (threadIdx.x == 0) *flag = (cnt > 8) ? 1 : 0;
}

// biases: flagged dtype -> fp32
__global__ __launch_bounds__(256) void cvt_weights_kernel(const void* __restrict__ src,
                                                          float* __restrict__ dst, int n,
                                                          const int* __restrict__ flag) {
  int t = blockIdx.x * 256 + threadIdx.x;
  if (t >= n) return;
  dst[t] = load_f(src, t, *flag);
}

// Transposed bf16 weights for MFMA B-operand (layout [subnet][n][k], k contiguous).
__global__ __launch_bounds__(256) void pt_win_kernel(const void* __restrict__ W_in,
                                                     bf16_t* __restrict__ dst,
                                                     const int* __restrict__ flag) {
  int t = blockIdx.x * 256 + threadIdx.x;
  if (t >= 4 * DH * DH) return;
  int s = t >> 14, n = (t >> 7) & 127, k = t & 127;
  float v = (k >= 3) ? load_f(W_in, (long)s * (125 * DH) + (k - 3) * DH + n, *flag) : 0.f;
  dst[t] = f2bf(v);
}
__global__ __launch_bounds__(256) void pt_wh_kernel(const void* __restrict__ W_h,
                                                    bf16_t* __restrict__ dst,
                                                    const int* __restrict__ flag) {
  int t = blockIdx.x * 256 + threadIdx.x;
  if (t >= 4 * DH * DH) return;
  int s = t >> 14, n = (t >> 7) & 127, k = t & 127;
  dst[t] = f2bf(load_f(W_h, (long)s * (DH * DH) + k * DH + n, *flag));
}
__global__ __launch_bounds__(256) void pt_wo_kernel(const void* __restrict__ W_out,
                                                    bf16_t* __restrict__ dst,
                                                    const int* __restrict__ flag) {
  int t = blockIdx.x * 256 + threadIdx.x;
  if (t >= 4 * 32 * DH) return;
  int s = t >> 12, n = (t >> 7) & 31, k = t & 127;
  dst[t] = f2bf(load_f(W_out, (long)s * (DH * 32) + k * 32 + n, *flag));
}

// output 0: exact passthrough of fv positions
__global__ __launch_bounds__(256) void cvt_out0_kernel(const void* __restrict__ fv,
                                                       void* __restrict__ out,
                                                       const int* __restrict__ flag) {
  int t = blockIdx.x * 256 + threadIdx.x;
  if (t >= NV0 * 3) return;
  int v = t / 3, c = t - v * 3;
  if (*flag) ((float*)out)[t] = ((const float*)fv)[v * DF + c];
  else ((bf16_t*)out)[t] = ((const bf16_t*)fv)[v * DF + c];
}

#define XST 136   // LDS row stride (bf16 elems): 272B

__device__ __forceinline__ f32x4 mfma16(short8 a, short8 b, f32x4 c) {
  return __builtin_amdgcn_mfma_f32_16x16x32_bf16(a, b, c, 0, 0, 0);
}

// One 128->128 layer IN-PLACE, M=32 rows per wave (2 MFMA m-tiles share every
// W load). The wave loads its ENTIRE 32x128 source tile into af registers
// before any store -> src buffer can be overwritten (no second LDS buffer).
__device__ __forceinline__ void mlp_layer2(
    short* buf,
    const bf16_t* __restrict__ Wt, const float* __restrict__ bias,
    int m0, int arow, int koff, int rrow)
{
  lds_fence();   // order af reads after previous phase's cross-lane LDS writes
  short8 af[2][4];
  #pragma unroll
  for (int mt = 0; mt < 2; ++mt)
    #pragma unroll
    for (int kq = 0; kq < 4; ++kq)
      af[mt][kq] = *(const short8*)(buf + (m0 + mt * 16 + arow) * XST + kq * 32 + koff);
  lds_fence();   // ALL tile reads issued before ANY in-place store (cross-lane WAR)
  #pragma unroll
  for (int ntl = 0; ntl < 8; ntl += 2) {
    f32x4 a00 = {0.f,0.f,0.f,0.f}, a01 = {0.f,0.f,0.f,0.f};
    f32x4 a10 = {0.f,0.f,0.f,0.f}, a11 = {0.f,0.f,0.f,0.f};
    #pragma unroll
    for (int kq = 0; kq < 4; ++kq) {
      short8 w0 = *(const short8*)(Wt + (ntl * 16 + arow) * DH + kq * 32 + koff);
      short8 w1 = *(const short8*)(Wt + ((ntl + 1) * 16 + arow) * DH + kq * 32 + koff);
      a00 = mfma16(af[0][kq], w0, a00);
      a01 = mfma16(af[0][kq], w1, a01);
      a10 = mfma16(af[1][kq], w0, a10);
      a11 = mfma16(af[1][kq], w1, a11);
    }
    int c0 = ntl * 16 + arow, c1 = c0 + 16;
    float bb0 = bias[c0], bb1 = bias[c1];
    #pragma unroll
    for (int r = 0; r < 4; ++r) {
      int rmA = m0 + rrow + r, rmB = m0 + 16 + rrow + r;
      buf[rmA * XST + c0] = (short)f2bf(fmaxf(a00[r] + bb0, 0.f));
      buf[rmA * XST + c1] = (short)f2bf(fmaxf(a01[r] + bb1, 0.f));
      buf[rmB * XST + c0] = (short)f2bf(fmaxf(a10[r] + bb0, 0.f));
      buf[rmB * XST + c1] = (short)f2bf(fmaxf(a11[r] + bb1, 0.f));
    }
  }
  lds_fence();   // order this layer's writes before next phase's reads
}

// Fused per-pass kernel. 128 flaps/block, M=32 per wave (wave wv owns rows
// [32wv, 32wv+32) end-to-end — strictly wave-local, barrier-free).
// IN-PLACE layers: single X buffer -> LDS ~40KB -> 4 blocks/CU (16 waves/CU).
// XCD-chunked bijective block swizzle for gather L2 locality.
template<int MODE, int RAW>
__global__ __launch_bounds__(256, 4) void mlp3_kernel(
    const void* __restrict__ fvin, const int* __restrict__ hfIdx, int nH,
    const bf16_t* __restrict__ Wt1, const bf16_t* __restrict__ Wt2,
    const bf16_t* __restrict__ Wt3,
    const float* __restrict__ b1, const float* __restrict__ b2,
    const float* __restrict__ b3,
    float* __restrict__ outp, float* __restrict__ dofp,
    const int* __restrict__ flag)
{
  __shared__ __align__(16) short Xl[128 * XST];  // X tile; later H; later Y (fp32, stride 68, row-own)
  __shared__ float LFl[128 * 9];
  __shared__ int   idxl[128];                    // center vertex per flap

  const int t = threadIdx.x;
  const int lane = t & 63;
  const int m0 = (t >> 6) * 32;
  const int arow = lane & 15;
  const int koff = (lane >> 4) * 8;
  const int rrow = (lane >> 4) * 4;
  const int isf32 = RAW ? *flag : 1;

  // bijective XCD-chunked swizzle: blocks on one XCD get a contiguous flap range
  const int nwg = gridDim.x;
  const int q = nwg >> 3, r = nwg & 7;
  const int xcd = blockIdx.x & 7;
  const int loc = blockIdx.x >> 3;
  const int bswz = (xcd < r ? xcd * (q + 1) : r * (q + 1) + (xcd - r) * q) + loc;
  const long h0 = (long)bswz * 128;

  // ---- phase 1: gather + in-register frame, wave-local (lane -> 2 flaps, vertex lane&3)
  #pragma unroll
  for (int half = 0; half < 2; ++half) {
    const int m = m0 + half * 16 + (lane >> 2);
    const int v = lane & 3;
    const long h = h0 + m;
    int vid = (h < nH) ? hfIdx[h * 4 + v] : 0;
    if (v == 0) idxl[m] = vid;
    float px, py, pz;
    u32 w[16];
    if (RAW && !isf32) {
      const uint4* src = (const uint4*)((const bf16_t*)fvin + (size_t)vid * DF);
      #pragma unroll
      for (int j = 0; j < 4; ++j) {
        uint4 x = src[j];
        w[j * 4 + 0] = x.x; w[j * 4 + 1] = x.y;
        w[j * 4 + 2] = x.z; w[j * 4 + 3] = x.w;
      }
      px = bf2f((bf16_t)(w[0] & 0xffff));
      py = bf2f((bf16_t)(w[0] >> 16));
      pz = bf2f((bf16_t)(w[1] & 0xffff));
    } else {
      const float4* src = (const float4*)((const float*)fvin + (size_t)vid * DF);
      float4 x0 = src[0];
      px = x0.x; py = x0.y; pz = x0.z;
      w[0] = pack2bf(x0.x, x0.y); w[1] = pack2bf(x0.z, x0.w);
      #pragma unroll
      for (int j = 1; j < 8; ++j) {
        float4 x = src[j];
        w[j * 2 + 0] = pack2bf(x.x, x.y);
        w[j * 2 + 1] = pack2bf(x.z, x.w);
      }
    }
    // local frame via 4-lane-group shuffles (redundant on all 4 lanes; cheap)
    const int bl = lane & ~3;
    F3 p0 = mkf3(__shfl(px, bl),     __shfl(py, bl),     __shfl(pz, bl));
    F3 p1 = mkf3(__shfl(px, bl | 1), __shfl(py, bl | 1), __shfl(pz, bl | 1));
    F3 p2 = mkf3(__shfl(px, bl | 2), __shfl(py, bl | 2), __shfl(pz, bl | 2));
    F3 p3 = mkf3(__shfl(px, bl | 3), __shfl(py, bl | 3), __shfl(pz, bl | 3));
    F3 e1  = f3sub(p1, p0);
    F3 B1  = f3nrm(e1);
    F3 fn0 = f3nrm(f3crs(e1, f3sub(p2, p0)));
    F3 fn1 = f3nrm(f3crs(f3sub(p0, p1), f3sub(p3, p1)));
    F3 B3  = f3nrm(f3add(fn0, fn1));
    F3 B2  = f3crs(B3, B1);
    if (v == 0) {
      float* lf = LFl + m * 9;
      lf[0] = B1.x; lf[1] = B1.y; lf[2] = B1.z;
      lf[3] = B2.x; lf[4] = B2.y; lf[5] = B2.z;
      lf[6] = B3.x; lf[7] = B3.y; lf[8] = B3.z;
      // v0 pos channels (k 0..2) hit zero rows of Wt1 -> keep raw, no need to clear
    } else {
      // channels v*32 + {0,1,2} = local coords of (p_v - p0); channel v*32+3 kept original
      F3 d = f3sub(mkf3(px, py, pz), p0);
      w[0] = pack2bf(f3dot(d, B1), f3dot(d, B2));
      w[1] = (w[1] & 0xffff0000u) | (u32)f2bf(f3dot(d, B3));
    }
    uint4* xrow = (uint4*)(Xl + m * XST + v * 32);   // 272B row stride: 16B-aligned
    #pragma unroll
    for (int j = 0; j < 4; ++j)
      xrow[j] = make_uint4(w[j * 4 + 0], w[j * 4 + 1], w[j * 4 + 2], w[j * 4 + 3]);
  }

  // ======== LAYER 1 / LAYER 2 (wave-local, in-place; fenced inside) ========
  mlp_layer2(Xl, Wt1, b1, m0, arow, koff, rrow);
  mlp_layer2(Xl, Wt2, b2, m0, arow, koff, rrow);

  // ======== LAYER 3: Y = H2 @ W3 + b3 (N=32, no relu); Y fp32 into row-own Xl storage ========
  {
    lds_fence();   // order af reads after layer-2's cross-lane Xl writes
    short8 af[2][4];
    #pragma unroll
    for (int mt = 0; mt < 2; ++mt)
      #pragma unroll
      for (int kq = 0; kq < 4; ++kq)
        af[mt][kq] = *(const short8*)(Xl + (m0 + mt * 16 + arow) * XST + kq * 32 + koff);
    f32x4 a00 = {0.f,0.f,0.f,0.f}, a01 = {0.f,0.f,0.f,0.f};
    f32x4 a10 = {0.f,0.f,0.f,0.f}, a11 = {0.f,0.f,0.f,0.f};
    #pragma unroll
    for (int kq = 0; kq < 4; ++kq) {
      short8 w0 = *(const short8*)(Wt3 + arow * DH + kq * 32 + koff);
      short8 w1 = *(const short8*)(Wt3 + (16 + arow) * DH + kq * 32 + koff);
      a00 = mfma16(af[0][kq], w0, a00);
      a01 = mfma16(af[0][kq], w1, a01);
      a10 = mfma16(af[1][kq], w0, a10);
      a11 = mfma16(af[1][kq], w1, a11);
    }
    lds_fence();   // af reads ordered before aliasing Yf writes
    float* Yf = (float*)Xl;
    float bb0 = b3[arow], bb1 = b3[16 + arow];
    #pragma unroll
    for (int r = 0; r < 4; ++r) {
      int rmA = m0 + rrow + r, rmB = m0 + 16 + rrow + r;
      Yf[rmA * 68 + arow]      = a00[r] + bb0;   // row rm's Y lives in row rm's Xl bytes
      Yf[rmA * 68 + 16 + arow] = a01[r] + bb1;
      Yf[rmB * 68 + arow]      = a10[r] + bb0;
      Yf[rmB * 68 + 16 + arow] = a11[r] + bb1;
    }
  }
  lds_fence();     // Yf writes ordered before epilogue's cross-lane reads

  // ======== epilogue: local2global + pool (wave-own 32 rows) ========
  float* Yf = (float*)Xl;
  #pragma unroll
  for (int i = 0; i < 16; ++i) {
    int row = m0 + i * 2 + (lane >> 5);
    long h = h0 + row;
    int ch = lane & 31;
    float val = 0.f;
    if (h < nH) {
      val = Yf[row * 68 + ch];
      if (ch < 3) {
        float y0 = Yf[row * 68 + 0], y1 = Yf[row * 68 + 1], y2 = Yf[row * 68 + 2];
        val = y0 * LFl[row * 9 + ch] + y1 * LFl[row * 9 + 3 + ch] + y2 * LFl[row * 9 + 6 + ch];
      }
    }
    if (MODE == 0) {
      if (h < nH) {
        atomicAdd(&outp[(size_t)idxl[row] * DF + ch], val);
        if (ch == 0) atomicAdd(&dofp[idxl[row]], 1.f);
      }
    } else {
      // half-edge pair (2e,2e+1) sits on lanes l / l+32 of this iteration:
      // combine in-wave -> plain store, no atomics, no zero-init of the odd buffer.
      float sum = val + __shfl_xor(val, 32);
      if (h < nH && lane < 32) {
        if (MODE == 1) outp[(size_t)(h >> 1) * DF + ch] = 0.5f * sum;
        else if (ch < 3) outp[(size_t)(h >> 1) * 3 + ch] = 0.5f * sum;
      }
    }
  }
}

// ---- finalize kernels ----
template<int RAW>
__global__ __launch_bounds__(256) void finalize_even_kernel(
    float* buf, const float* __restrict__ dof,
    const void* __restrict__ prevraw, const float* __restrict__ prevf,
    void* __restrict__ out, int outbase, const int* __restrict__ flag, int nV) {
  int t = blockIdx.x * 256 + threadIdx.x;
  if (t >= nV * DF) return;
  int v = t >> 5, c = t & 31;
  float val = buf[t] / fmaxf(dof[v], 1.0f);
  if (c < 3) {
    float pp = RAW ? load_f(prevraw, (long)v * DF + c, *flag) : prevf[(long)v * DF + c];
    val += pp;
    store_out(out, (long)outbase + (long)v * 3 + c, val, *flag);
  }
  buf[t] = val;
}

__global__ __launch_bounds__(256) void finalize_odd_full_kernel(
    float* oddbuf, const int* __restrict__ hfIdx,
    const float* fveven, void* __restrict__ out, int outbase,
    const int* __restrict__ flag, int nE, int nVeven) {
  int t = blockIdx.x * 256 + threadIdx.x;
  if (t >= nE * DF) return;
  int e = t >> 5, c = t & 31;
  float val = oddbuf[t];
  if (c < 3) {
    int a0 = hfIdx[(size_t)(2 * e) * 4 + 0];
    int a1 = hfIdx[(size_t)(2 * e) * 4 + 1];
    int b0 = hfIdx[(size_t)(2 * e + 1) * 4 + 0];
    int b1 = hfIdx[(size_t)(2 * e + 1) * 4 + 1];
    val += 0.25f * (fveven[(size_t)a0 * DF + c] + fveven[(size_t)a1 * DF + c] +
                    fveven[(size_t)b0 * DF + c] + fveven[(size_t)b1 * DF + c]);
    store_out(out, (long)outbase + (long)(nVeven + e) * 3 + c, val, *flag);
  }
  oddbuf[t] = val;
}

__global__ __launch_bounds__(256) void finalize_odd_pos_kernel(
    const float* __restrict__ odd3, const int* __restrict__ hfIdx,
    const float* __restrict__ fveven, void* __restrict__ out, int outbase,
    const int* __restrict__ flag, int nE, int nVeven) {
  int t = blockIdx.x * 256 + threadIdx.x;
  if (t >= nE * 3) return;
  int e = t / 3, c = t - e * 3;
  int a0 = hfIdx[(size_t)(2 * e) * 4 + 0];
  int a1 = hfIdx[(size_t)(2 * e) * 4 + 1];
  int b0 = hfIdx[(size_t)(2 * e + 1) * 4 + 0];
  int b1 = hfIdx[(size_t)(2 * e + 1) * 4 + 1];
  float val = odd3[t] + 0.25f * (fveven[(size_t)a0 * DF + c] + fveven[(size_t)a1 * DF + c] +
                                 fveven[(size_t)b0 * DF + c] + fveven[(size_t)b1 * DF + c]);
  store_out(out, (long)outbase + (long)(nVeven + e) * 3 + c, val, *flag);
}

extern "C" void kernel_launch(void* const* d_in, const int* in_sizes, int n_in,
                              void* d_out, int out_size, void* d_ws, size_t ws_size,
                              hipStream_t stream) {
  const void* fv    = d_in[0];
  const void* W_in  = d_in[1];
  const void* b_in  = d_in[2];
  const void* W_h   = d_in[3];
  const void* b_h   = d_in[4];
  const void* W_out = d_in[5];
  const void* b_out = d_in[6];
  const int* hf0 = (const int*)d_in[7];
  const int* hf1 = (const int*)d_in[8];
  (void)in_sizes; (void)n_in; (void)out_size;

  // workspace (~29.8 MiB)
  float* fv1   = (float*)d_ws;            // 3,840,000 (120000x32)
  float* fvup2 = fv1   + 3840000;         // 3,840,000
  float* dof   = fvup2 + 3840000;         // 120,000
  float* bif   = dof   + 120000;          // 512
  float* bhf   = bif   + 512;             // 512
  float* bof   = bhf   + 512;             // 128
  int*   flag  = (int*)(bof + 128);       // 4 ints (1 used)
  bf16_t* Wti  = (bf16_t*)(flag + 4);     // 4x128x128
  bf16_t* Wth  = Wti + 65536;             // 4x128x128
  bf16_t* Wto  = Wth + 65536;             // 4x32x128
  const size_t needed = ((size_t)3840000 * 2 + 120000 + 512 * 2 + 128 + 4) * 4
                      + (65536 * 2 + 16384) * 2;
  if (ws_size < needed) return;

  float* odd_acc0 = fv1 + (size_t)NV0 * DF;  // level-0 odd region (90000x32)

  // ---- dtype detect + weight staging
  detect_kernel<<<1, 256, 0, stream>>>((const u32*)fv, flag);
  pt_win_kernel<<<256, 256, 0, stream>>>(W_in, Wti, flag);
  pt_wh_kernel<<<256, 256, 0, stream>>>(W_h, Wth, flag);
  pt_wo_kernel<<<64, 256, 0, stream>>>(W_out, Wto, flag);
  cvt_weights_kernel<<<2, 256, 0, stream>>>(b_in, bif, 512, flag);
  cvt_weights_kernel<<<2, 256, 0, stream>>>(b_h, bhf, 512, flag);
  cvt_weights_kernel<<<1, 256, 0, stream>>>(b_out, bof, 128, flag);
  cvt_out0_kernel<<<(NV0 * 3 + 255) / 256, 256, 0, stream>>>(fv, d_out, flag);

  const int G0 = (H0 + 127) / 128, G1 = (H1 + 127) / 128;

  // ================= level 0 =================
  hipMemsetAsync(fv1, 0, (size_t)NV0 * DF * 4, stream);
  hipMemsetAsync(dof, 0, (size_t)NV0 * 4, stream);
  mlp3_kernel<0, 1><<<G0, 256, 0, stream>>>(fv, hf0, H0,
      Wti + 0 * 16384, Wth + 0 * 16384, Wto + 0 * 4096,
      bif + 0 * DH, bhf + 0 * DH, bof + 0 * DF, fv1, dof, flag);
  finalize_even_kernel<1><<<(NV0 * DF + 255) / 256, 256, 0, stream>>>(
      fv1, dof, fv, nullptr, d_out, 90000, flag, NV0);
  // odd pass fully overwrites odd_acc0 (pair-combined plain stores) -> no memset
  mlp3_kernel<1, 0><<<G0, 256, 0, stream>>>(fv1, hf0, H0,
      Wti + 1 * 16384, Wth + 1 * 16384, Wto + 1 * 4096,
      bif + 1 * DH, bhf + 1 * DH, bof + 1 * DF, odd_acc0, nullptr, flag);
  finalize_odd_full_kernel<<<(NE0 * DF + 255) / 256, 256, 0, stream>>>(
      odd_acc0, hf0, fv1, d_out, 90000, flag, NE0, NV0);

  // ================= level 1 =================
  hipMemsetAsync(fvup2, 0, (size_t)NV1 * DF * 4, stream);
  hipMemsetAsync(dof, 0, (size_t)NV1 * 4, stream);
  mlp3_kernel<0, 0><<<G1, 256, 0, stream>>>(fv1, hf1, H1,
      Wti + 2 * 16384, Wth + 2 * 16384, Wto + 2 * 4096,
      bif + 2 * DH, bhf + 2 * DH, bof + 2 * DF, fvup2, dof, flag);
  finalize_even_kernel<0><<<(NV1 * DF + 255) / 256, 256, 0, stream>>>(
      fvup2, dof, nullptr, fv1, d_out, 450000, flag, NV1);
  // odd3 region fully overwritten by MODE 2 stores -> no memset
  mlp3_kernel<2, 0><<<G1, 256, 0, stream>>>(fvup2, hf1, H1,
      Wti + 3 * 16384, Wth + 3 * 16384, Wto + 3 * 4096,
      bif + 3 * DH, bhf + 3 * DH, bof + 3 * DF, fv1, nullptr, flag);
  finalize_odd_pos_kernel<<<(NE1 * 3 + 255) / 256, 256, 0, stream>>>(
      fv1, hf1, fvup2, d_out, 450000, flag, NE1, NV1);
}

// Round 9
// 631.190 us; speedup vs baseline: 1.0817x; 1.0123x over previous
//
#include <hip/hip_runtime.h>

#define NV0 30000
#define NE0 90000
#define H0 (2*NE0)      // 180000
#define NV1 (NV0+NE0)   // 120000
#define NE1 (3*NE0)     // 270000
#define H1 (2*NE1)      // 540000
#define DF 32
#define DH 128

typedef unsigned short bf16_t;
typedef unsigned int u32;
typedef __attribute__((ext_vector_type(8))) short short8;
typedef __attribute__((ext_vector_type(4))) float f32x4;

__device__ __forceinline__ float bf2f(bf16_t b) { return __uint_as_float(((u32)b) << 16); }
__device__ __forceinline__ bf16_t f2bf(float f) {
  u32 u = __float_as_uint(f);
  return (bf16_t)((u + 0x7fffu + ((u >> 16) & 1u)) >> 16);
}
__device__ __forceinline__ u32 pack2bf(float a, float b) {
  return (u32)f2bf(a) | ((u32)f2bf(b) << 16);
}
__device__ __forceinline__ float load_f(const void* p, long i, int isf32) {
  return isf32 ? ((const float*)p)[i] : bf2f(((const bf16_t*)p)[i]);
}
__device__ __forceinline__ void store_out(void* p, long i, float v, int isf32) {
  if (isf32) ((float*)p)[i] = v;
  else ((bf16_t*)p)[i] = f2bf(v);
}

// Compile-time ordering fence for cross-lane LDS RAW/WAR hazards within a wave.
// HW processes a wave's DS ops in issue order; we only need the COMPILER not to
// reorder ds_read/ds_write across this point. Wavefront-scope fence orders all
// memory ops in IR/MIR without forcing cross-wave cache semantics.
__device__ __forceinline__ void lds_fence() {
  __builtin_amdgcn_fence(__ATOMIC_ACQ_REL, "wavefront");
  __builtin_amdgcn_sched_barrier(0);
}

struct F3 { float x, y, z; };
__device__ __forceinline__ F3 mkf3(float x, float y, float z){ F3 r; r.x=x; r.y=y; r.z=z; return r; }
__device__ __forceinline__ F3 f3sub(F3 a, F3 b){ return mkf3(a.x-b.x, a.y-b.y, a.z-b.z); }
__device__ __forceinline__ F3 f3add(F3 a, F3 b){ return mkf3(a.x+b.x, a.y+b.y, a.z+b.z); }
__device__ __forceinline__ float f3dot(F3 a, F3 b){ return a.x*b.x + a.y*b.y + a.z*b.z; }
__device__ __forceinline__ F3 f3crs(F3 a, F3 b){
  return mkf3(a.y*b.z - a.z*b.y, a.z*b.x - a.x*b.z, a.x*b.y - a.y*b.x);
}
__device__ __forceinline__ F3 f3nrm(F3 a){
  float r = rsqrtf(f3dot(a,a));
  return mkf3(a.x*r, a.y*r, a.z*r);
}

// ---- dtype detection
__global__ __launch_bounds__(256) void detect_kernel(const u32* __restrict__ fvw,
                                                     int* __restrict__ flag) {
  __shared__ int cnt;
  if (threadIdx.x == 0) cnt = 0;
  __syncthreads();
  int c = 0;
  #pragma unroll
  for (int j = 0; j < 2; ++j) {
    u32 w = fvw[threadIdx.x * 2 + j];
    u32 e = (w >> 7) & 0xffu;
    if (e > 140u) c++;
  }
  if (c) atomicAdd(&cnt, c);
  __syncthreads();
  if (threadIdx.x == 0) *flag = (cnt > 8) ? 1 : 0;
}

// biases: flagged dtype -> fp32
__global__ __launch_bounds__(256) void cvt_weights_kernel(const void* __restrict__ src,
                                                          float* __restrict__ dst, int n,
                                                          const int* __restrict__ flag) {
  int t = blockIdx.x * 256 + threadIdx.x;
  if (t >= n) return;
  dst[t] = load_f(src, t, *flag);
}

// Transposed bf16 weights for MFMA B-operand (layout [subnet][n][k], k contiguous).
__global__ __launch_bounds__(256) void pt_win_kernel(const void* __restrict__ W_in,
                                                     bf16_t* __restrict__ dst,
                                                     const int* __restrict__ flag) {
  int t = blockIdx.x * 256 + threadIdx.x;
  if (t >= 4 * DH * DH) return;
  int s = t >> 14, n = (t >> 7) & 127, k = t & 127;
  float v = (k >= 3) ? load_f(W_in, (long)s * (125 * DH) + (k - 3) * DH + n, *flag) : 0.f;
  dst[t] = f2bf(v);
}
__global__ __launch_bounds__(256) void pt_wh_kernel(const void* __restrict__ W_h,
                                                    bf16_t* __restrict__ dst,
                                                    const int* __restrict__ flag) {
  int t = blockIdx.x * 256 + threadIdx.x;
  if (t >= 4 * DH * DH) return;
  int s = t >> 14, n = (t >> 7) & 127, k = t & 127;
  dst[t] = f2bf(load_f(W_h, (long)s * (DH * DH) + k * DH + n, *flag));
}
__global__ __launch_bounds__(256) void pt_wo_kernel(const void* __restrict__ W_out,
                                                    bf16_t* __restrict__ dst,
                                                    const int* __restrict__ flag) {
  int t = blockIdx.x * 256 + threadIdx.x;
  if (t >= 4 * 32 * DH) return;
  int s = t >> 12, n = (t >> 7) & 31, k = t & 127;
  dst[t] = f2bf(load_f(W_out, (long)s * (DH * 32) + k * 32 + n, *flag));
}

// output 0: exact passthrough of fv positions
__global__ __launch_bounds__(256) void cvt_out0_kernel(const void* __restrict__ fv,
                                                       void* __restrict__ out,
                                                       const int* __restrict__ flag) {
  int t = blockIdx.x * 256 + threadIdx.x;
  if (t >= NV0 * 3) return;
  int v = t / 3, c = t - v * 3;
  if (*flag) ((float*)out)[t] = ((const float*)fv)[v * DF + c];
  else ((bf16_t*)out)[t] = ((const bf16_t*)fv)[v * DF + c];
}

#define XST 136   // LDS row stride (bf16 elems): 272B

__device__ __forceinline__ f32x4 mfma16(short8 a, short8 b, f32x4 c) {
  return __builtin_amdgcn_mfma_f32_16x16x32_bf16(a, b, c, 0, 0, 0);
}

// One 128->128 layer IN-PLACE, M=32 rows per wave (2 MFMA m-tiles share every
// W load). The wave loads its ENTIRE 32x128 source tile into af registers
// before any store -> src buffer can be overwritten (no second LDS buffer).
__device__ __forceinline__ void mlp_layer2(
    short* buf,
    const bf16_t* __restrict__ Wt, const float* __restrict__ bias,
    int m0, int arow, int koff, int rrow)
{
  lds_fence();   // order af reads after previous phase's cross-lane LDS writes
  short8 af[2][4];
  #pragma unroll
  for (int mt = 0; mt < 2; ++mt)
    #pragma unroll
    for (int kq = 0; kq < 4; ++kq)
      af[mt][kq] = *(const short8*)(buf + (m0 + mt * 16 + arow) * XST + kq * 32 + koff);
  lds_fence();   // ALL tile reads issued before ANY in-place store (cross-lane WAR)
  #pragma unroll
  for (int ntl = 0; ntl < 8; ntl += 2) {
    f32x4 a00 = {0.f,0.f,0.f,0.f}, a01 = {0.f,0.f,0.f,0.f};
    f32x4 a10 = {0.f,0.f,0.f,0.f}, a11 = {0.f,0.f,0.f,0.f};
    #pragma unroll
    for (int kq = 0; kq < 4; ++kq) {
      short8 w0 = *(const short8*)(Wt + (ntl * 16 + arow) * DH + kq * 32 + koff);
      short8 w1 = *(const short8*)(Wt + ((ntl + 1) * 16 + arow) * DH + kq * 32 + koff);
      a00 = mfma16(af[0][kq], w0, a00);
      a01 = mfma16(af[0][kq], w1, a01);
      a10 = mfma16(af[1][kq], w0, a10);
      a11 = mfma16(af[1][kq], w1, a11);
    }
    int c0 = ntl * 16 + arow, c1 = c0 + 16;
    float bb0 = bias[c0], bb1 = bias[c1];
    #pragma unroll
    for (int r = 0; r < 4; ++r) {
      int rmA = m0 + rrow + r, rmB = m0 + 16 + rrow + r;
      buf[rmA * XST + c0] = (short)f2bf(fmaxf(a00[r] + bb0, 0.f));
      buf[rmA * XST + c1] = (short)f2bf(fmaxf(a01[r] + bb1, 0.f));
      buf[rmB * XST + c0] = (short)f2bf(fmaxf(a10[r] + bb0, 0.f));
      buf[rmB * XST + c1] = (short)f2bf(fmaxf(a11[r] + bb1, 0.f));
    }
  }
  lds_fence();   // order this layer's writes before next phase's reads
}

// Fused per-pass kernel. 128 flaps/block, M=32 per wave (wave wv owns rows
// [32wv, 32wv+32) end-to-end — strictly wave-local, barrier-free).
// IN-PLACE layers: single X buffer -> LDS ~40KB -> 4 blocks/CU (16 waves/CU).
// RAW=1: gather from raw input (dtype via flag). RAW=0: gather the 32 MLP
// channels from the 64B bf16 MIRROR (1 L2-miss granule/vertex instead of 2)
// and POSITIONS from the L2-resident f32 posf array — frame math stays exact
// f32, bit-identical to the all-f32 version (round-8's bf16-frame NaN fixed).
template<int MODE, int RAW>
__global__ __launch_bounds__(256, 4) void mlp3_kernel(
    const void* __restrict__ fvin, const float* __restrict__ posf,
    const int* __restrict__ hfIdx, int nH,
    const bf16_t* __restrict__ Wt1, const bf16_t* __restrict__ Wt2,
    const bf16_t* __restrict__ Wt3,
    const float* __restrict__ b1, const float* __restrict__ b2,
    const float* __restrict__ b3,
    float* __restrict__ outp, float* __restrict__ dofp,
    const int* __restrict__ flag)
{
  __shared__ __align__(16) short Xl[128 * XST];  // X tile; later H; later Y (fp32, stride 68, row-own)
  __shared__ float LFl[128 * 9];
  __shared__ int   idxl[128];                    // center vertex per flap

  const int t = threadIdx.x;
  const int lane = t & 63;
  const int m0 = (t >> 6) * 32;
  const int arow = lane & 15;
  const int koff = (lane >> 4) * 8;
  const int rrow = (lane >> 4) * 4;
  const int isf32 = RAW ? *flag : 0;

  // bijective XCD-chunked swizzle: blocks on one XCD get a contiguous flap range
  const int nwg = gridDim.x;
  const int q = nwg >> 3, r = nwg & 7;
  const int xcd = blockIdx.x & 7;
  const int loc = blockIdx.x >> 3;
  const int bswz = (xcd < r ? xcd * (q + 1) : r * (q + 1) + (xcd - r) * q) + loc;
  const long h0 = (long)bswz * 128;

  // ---- phase 1: gather + in-register frame, wave-local (lane -> 2 flaps, vertex lane&3)
  #pragma unroll
  for (int half = 0; half < 2; ++half) {
    const int m = m0 + half * 16 + (lane >> 2);
    const int v = lane & 3;
    const long h = h0 + m;
    int vid = (h < nH) ? hfIdx[h * 4 + v] : 0;
    if (v == 0) idxl[m] = vid;
    float px, py, pz;
    u32 w[16];
    if (RAW) {
      if (!isf32) {
        const uint4* src = (const uint4*)((const bf16_t*)fvin + (size_t)vid * DF);
        #pragma unroll
        for (int j = 0; j < 4; ++j) {
          uint4 x = src[j];
          w[j * 4 + 0] = x.x; w[j * 4 + 1] = x.y;
          w[j * 4 + 2] = x.z; w[j * 4 + 3] = x.w;
        }
        px = bf2f((bf16_t)(w[0] & 0xffff));
        py = bf2f((bf16_t)(w[0] >> 16));
        pz = bf2f((bf16_t)(w[1] & 0xffff));
      } else {
        const float4* src = (const float4*)((const float*)fvin + (size_t)vid * DF);
        float4 x0 = src[0];
        px = x0.x; py = x0.y; pz = x0.z;
        w[0] = pack2bf(x0.x, x0.y); w[1] = pack2bf(x0.z, x0.w);
        #pragma unroll
        for (int j = 1; j < 8; ++j) {
          float4 x = src[j];
          w[j * 2 + 0] = pack2bf(x.x, x.y);
          w[j * 2 + 1] = pack2bf(x.z, x.w);
        }
      }
    } else {
      // bf16 mirror row (channel values identical to f2bf of the f32 source)
      const uint4* src = (const uint4*)((const bf16_t*)fvin + (size_t)vid * DF);
      #pragma unroll
      for (int j = 0; j < 4; ++j) {
        uint4 x = src[j];
        w[j * 4 + 0] = x.x; w[j * 4 + 1] = x.y;
        w[j * 4 + 2] = x.z; w[j * 4 + 3] = x.w;
      }
      // exact f32 positions from the L2-resident side array
      px = posf[(size_t)vid * 3 + 0];
      py = posf[(size_t)vid * 3 + 1];
      pz = posf[(size_t)vid * 3 + 2];
    }
    // local frame via 4-lane-group shuffles (redundant on all 4 lanes; cheap)
    const int bl = lane & ~3;
    F3 p0 = mkf3(__shfl(px, bl),     __shfl(py, bl),     __shfl(pz, bl));
    F3 p1 = mkf3(__shfl(px, bl | 1), __shfl(py, bl | 1), __shfl(pz, bl | 1));
    F3 p2 = mkf3(__shfl(px, bl | 2), __shfl(py, bl | 2), __shfl(pz, bl | 2));
    F3 p3 = mkf3(__shfl(px, bl | 3), __shfl(py, bl | 3), __shfl(pz, bl | 3));
    F3 e1  = f3sub(p1, p0);
    F3 B1  = f3nrm(e1);
    F3 fn0 = f3nrm(f3crs(e1, f3sub(p2, p0)));
    F3 fn1 = f3nrm(f3crs(f3sub(p0, p1), f3sub(p3, p1)));
    F3 B3  = f3nrm(f3add(fn0, fn1));
    F3 B2  = f3crs(B3, B1);
    if (v == 0) {
      float* lf = LFl + m * 9;
      lf[0] = B1.x; lf[1] = B1.y; lf[2] = B1.z;
      lf[3] = B2.x; lf[4] = B2.y; lf[5] = B2.z;
      lf[6] = B3.x; lf[7] = B3.y; lf[8] = B3.z;
      // v0 pos channels (k 0..2) hit zero rows of Wt1 -> keep raw, no need to clear
    } else {
      // channels v*32 + {0,1,2} = local coords of (p_v - p0); channel v*32+3 kept original
      F3 d = f3sub(mkf3(px, py, pz), p0);
      w[0] = pack2bf(f3dot(d, B1), f3dot(d, B2));
      w[1] = (w[1] & 0xffff0000u) | (u32)f2bf(f3dot(d, B3));
    }
    uint4* xrow = (uint4*)(Xl + m * XST + v * 32);   // 272B row stride: 16B-aligned
    #pragma unroll
    for (int j = 0; j < 4; ++j)
      xrow[j] = make_uint4(w[j * 4 + 0], w[j * 4 + 1], w[j * 4 + 2], w[j * 4 + 3]);
  }

  // ======== LAYER 1 / LAYER 2 (wave-local, in-place; fenced inside) ========
  mlp_layer2(Xl, Wt1, b1, m0, arow, koff, rrow);
  mlp_layer2(Xl, Wt2, b2, m0, arow, koff, rrow);

  // ======== LAYER 3: Y = H2 @ W3 + b3 (N=32, no relu); Y fp32 into row-own Xl storage ========
  {
    lds_fence();   // order af reads after layer-2's cross-lane Xl writes
    short8 af[2][4];
    #pragma unroll
    for (int mt = 0; mt < 2; ++mt)
      #pragma unroll
      for (int kq = 0; kq < 4; ++kq)
        af[mt][kq] = *(const short8*)(Xl + (m0 + mt * 16 + arow) * XST + kq * 32 + koff);
    f32x4 a00 = {0.f,0.f,0.f,0.f}, a01 = {0.f,0.f,0.f,0.f};
    f32x4 a10 = {0.f,0.f,0.f,0.f}, a11 = {0.f,0.f,0.f,0.f};
    #pragma unroll
    for (int kq = 0; kq < 4; ++kq) {
      short8 w0 = *(const short8*)(Wt3 + arow * DH + kq * 32 + koff);
      short8 w1 = *(const short8*)(Wt3 + (16 + arow) * DH + kq * 32 + koff);
      a00 = mfma16(af[0][kq], w0, a00);
      a01 = mfma16(af[0][kq], w1, a01);
      a10 = mfma16(af[1][kq], w0, a10);
      a11 = mfma16(af[1][kq], w1, a11);
    }
    lds_fence();   // af reads ordered before aliasing Yf writes
    float* Yf = (float*)Xl;
    float bb0 = b3[arow], bb1 = b3[16 + arow];
    #pragma unroll
    for (int r = 0; r < 4; ++r) {
      int rmA = m0 + rrow + r, rmB = m0 + 16 + rrow + r;
      Yf[rmA * 68 + arow]      = a00[r] + bb0;   // row rm's Y lives in row rm's Xl bytes
      Yf[rmA * 68 + 16 + arow] = a01[r] + bb1;
      Yf[rmB * 68 + arow]      = a10[r] + bb0;
      Yf[rmB * 68 + 16 + arow] = a11[r] + bb1;
    }
  }
  lds_fence();     // Yf writes ordered before epilogue's cross-lane reads

  // ======== epilogue: local2global + pool (wave-own 32 rows) ========
  float* Yf = (float*)Xl;
  #pragma unroll
  for (int i = 0; i < 16; ++i) {
    int row = m0 + i * 2 + (lane >> 5);
    long h = h0 + row;
    int ch = lane & 31;
    float val = 0.f;
    if (h < nH) {
      val = Yf[row * 68 + ch];
      if (ch < 3) {
        float y0 = Yf[row * 68 + 0], y1 = Yf[row * 68 + 1], y2 = Yf[row * 68 + 2];
        val = y0 * LFl[row * 9 + ch] + y1 * LFl[row * 9 + 3 + ch] + y2 * LFl[row * 9 + 6 + ch];
      }
    }
    if (MODE == 0) {
      if (h < nH) {
        atomicAdd(&outp[(size_t)idxl[row] * DF + ch], val);
        if (ch == 0) atomicAdd(&dofp[idxl[row]], 1.f);
      }
    } else {
      // half-edge pair (2e,2e+1) sits on lanes l / l+32 of this iteration:
      // combine in-wave -> plain store, no atomics, no zero-init of the odd buffer.
      float sum = val + __shfl_xor(val, 32);
      if (h < nH && lane < 32) {
        if (MODE == 1) outp[(size_t)(h >> 1) * DF + ch] = 0.5f * sum;
        else if (ch < 3) outp[(size_t)(h >> 1) * 3 + ch] = 0.5f * sum;
      }
    }
  }
}

// ---- finalize kernels (also emit the bf16 channel mirror + f32 pos array) ----
template<int RAW>
__global__ __launch_bounds__(256) void finalize_even_kernel(
    float* buf, const float* __restrict__ dof,
    const void* __restrict__ prevraw, const float* __restrict__ prevf,
    void* __restrict__ out, int outbase, const int* __restrict__ flag, int nV,
    bf16_t* __restrict__ mirror, float* __restrict__ posf) {
  int t = blockIdx.x * 256 + threadIdx.x;
  if (t >= nV * DF) return;
  int v = t >> 5, c = t & 31;
  float val = buf[t] / fmaxf(dof[v], 1.0f);
  if (c < 3) {
    float pp = RAW ? load_f(prevraw, (long)v * DF + c, *flag) : prevf[(long)v * DF + c];
    val += pp;
    store_out(out, (long)outbase + (long)v * 3 + c, val, *flag);
    posf[(size_t)v * 3 + c] = val;
  }
  buf[t] = val;
  mirror[t] = f2bf(val);
}

__global__ __launch_bounds__(256) void finalize_odd_full_kernel(
    float* oddbuf, const int* __restrict__ hfIdx,
    const float* fveven, void* __restrict__ out, int outbase,
    const int* __restrict__ flag, int nE, int nVeven,
    bf16_t* __restrict__ mirror_off, float* __restrict__ posf_off) {
  int t = blockIdx.x * 256 + threadIdx.x;
  if (t >= nE * DF) return;
  int e = t >> 5, c = t & 31;
  float val = oddbuf[t];
  if (c < 3) {
    int a0 = hfIdx[(size_t)(2 * e) * 4 + 0];
    int a1 = hfIdx[(size_t)(2 * e) * 4 + 1];
    int b0 = hfIdx[(size_t)(2 * e + 1) * 4 + 0];
    int b1 = hfIdx[(size_t)(2 * e + 1) * 4 + 1];
    val += 0.25f * (fveven[(size_t)a0 * DF + c] + fveven[(size_t)a1 * DF + c] +
                    fveven[(size_t)b0 * DF + c] + fveven[(size_t)b1 * DF + c]);
    store_out(out, (long)outbase + (long)(nVeven + e) * 3 + c, val, *flag);
    posf_off[(size_t)e * 3 + c] = val;
  }
  oddbuf[t] = val;
  mirror_off[t] = f2bf(val);
}

__global__ __launch_bounds__(256) void finalize_odd_pos_kernel(
    const float* __restrict__ odd3, const int* __restrict__ hfIdx,
    const float* __restrict__ fveven, void* __restrict__ out, int outbase,
    const int* __restrict__ flag, int nE, int nVeven) {
  int t = blockIdx.x * 256 + threadIdx.x;
  if (t >= nE * 3) return;
  int e = t / 3, c = t - e * 3;
  int a0 = hfIdx[(size_t)(2 * e) * 4 + 0];
  int a1 = hfIdx[(size_t)(2 * e) * 4 + 1];
  int b0 = hfIdx[(size_t)(2 * e + 1) * 4 + 0];
  int b1 = hfIdx[(size_t)(2 * e + 1) * 4 + 1];
  float val = odd3[t] + 0.25f * (fveven[(size_t)a0 * DF + c] + fveven[(size_t)a1 * DF + c] +
                                 fveven[(size_t)b0 * DF + c] + fveven[(size_t)b1 * DF + c]);
  store_out(out, (long)outbase + (long)(nVeven + e) * 3 + c, val, *flag);
}

extern "C" void kernel_launch(void* const* d_in, const int* in_sizes, int n_in,
                              void* d_out, int out_size, void* d_ws, size_t ws_size,
                              hipStream_t stream) {
  const void* fv    = d_in[0];
  const void* W_in  = d_in[1];
  const void* b_in  = d_in[2];
  const void* W_h   = d_in[3];
  const void* b_h   = d_in[4];
  const void* W_out = d_in[5];
  const void* b_out = d_in[6];
  const int* hf0 = (const int*)d_in[7];
  const int* hf1 = (const int*)d_in[8];
  (void)in_sizes; (void)n_in; (void)out_size;

  // workspace (~38.7 MiB)
  float* fv1   = (float*)d_ws;            // 3,840,000 (120000x32)
  float* fvup2 = fv1   + 3840000;         // 3,840,000
  float* dof   = fvup2 + 3840000;         // 120,000
  float* bif   = dof   + 120000;          // 512
  float* bhf   = bif   + 512;             // 512
  float* bof   = bhf   + 512;             // 128
  int*   flag  = (int*)(bof + 128);       // 4 ints (1 used)
  bf16_t* Wti  = (bf16_t*)(flag + 4);     // 4x128x128
  bf16_t* Wth  = Wti + 65536;             // 4x128x128
  bf16_t* Wto  = Wth + 65536;             // 4x32x128
  bf16_t* fvbf = Wto + 16384;             // 120000x32 bf16 channel mirror (7.68 MB)
  float* posf  = (float*)(fvbf + 3840000); // 120000x3 f32 positions (1.44 MB, L2-resident)
  const size_t needed = ((size_t)3840000 * 2 + 120000 + 512 * 2 + 128 + 4) * 4
                      + (65536 * 2 + 16384) * 2 + (size_t)3840000 * 2
                      + (size_t)360000 * 4;
  if (ws_size < needed) return;

  float* odd_acc0 = fv1 + (size_t)NV0 * DF;  // level-0 odd region (90000x32)

  // ---- dtype detect + weight staging
  detect_kernel<<<1, 256, 0, stream>>>((const u32*)fv, flag);
  pt_win_kernel<<<256, 256, 0, stream>>>(W_in, Wti, flag);
  pt_wh_kernel<<<256, 256, 0, stream>>>(W_h, Wth, flag);
  pt_wo_kernel<<<64, 256, 0, stream>>>(W_out, Wto, flag);
  cvt_weights_kernel<<<2, 256, 0, stream>>>(b_in, bif, 512, flag);
  cvt_weights_kernel<<<2, 256, 0, stream>>>(b_h, bhf, 512, flag);
  cvt_weights_kernel<<<1, 256, 0, stream>>>(b_out, bof, 128, flag);
  cvt_out0_kernel<<<(NV0 * 3 + 255) / 256, 256, 0, stream>>>(fv, d_out, flag);

  const int G0 = (H0 + 127) / 128, G1 = (H1 + 127) / 128;

  // ================= level 0 =================
  hipMemsetAsync(fv1, 0, (size_t)NV0 * DF * 4, stream);
  hipMemsetAsync(dof, 0, (size_t)NV0 * 4, stream);
  mlp3_kernel<0, 1><<<G0, 256, 0, stream>>>(fv, nullptr, hf0, H0,
      Wti + 0 * 16384, Wth + 0 * 16384, Wto + 0 * 4096,
      bif + 0 * DH, bhf + 0 * DH, bof + 0 * DF, fv1, dof, flag);
  finalize_even_kernel<1><<<(NV0 * DF + 255) / 256, 256, 0, stream>>>(
      fv1, dof, fv, nullptr, d_out, 90000, flag, NV0, fvbf, posf);
  // odd pass gathers mirror channels + posf positions (rows 0..NV0 ready);
  // fully overwrites odd_acc0 (pair-combined plain stores) -> no memset
  mlp3_kernel<1, 0><<<G0, 256, 0, stream>>>(fvbf, posf, hf0, H0,
      Wti + 1 * 16384, Wth + 1 * 16384, Wto + 1 * 4096,
      bif + 1 * DH, bhf + 1 * DH, bof + 1 * DF, odd_acc0, nullptr, flag);
  finalize_odd_full_kernel<<<(NE0 * DF + 255) / 256, 256, 0, stream>>>(
      odd_acc0, hf0, fv1, d_out, 90000, flag, NE0, NV0,
      fvbf + (size_t)NV0 * DF, posf + (size_t)NV0 * 3);

  // ================= level 1 =================
  hipMemsetAsync(fvup2, 0, (size_t)NV1 * DF * 4, stream);
  hipMemsetAsync(dof, 0, (size_t)NV1 * 4, stream);
  // even pass gathers mirror+posf (rows 0..NV1 complete: even + odd finalize)
  mlp3_kernel<0, 0><<<G1, 256, 0, stream>>>(fvbf, posf, hf1, H1,
      Wti + 2 * 16384, Wth + 2 * 16384, Wto + 2 * 4096,
      bif + 2 * DH, bhf + 2 * DH, bof + 2 * DF, fvup2, dof, flag);
  // re-targets mirror+posf to fvup2 values (rows 0..NV1)
  finalize_even_kernel<0><<<(NV1 * DF + 255) / 256, 256, 0, stream>>>(
      fvup2, dof, nullptr, fv1, d_out, 450000, flag, NV1, fvbf, posf);
  // odd3 region fully overwritten by MODE 2 stores -> no memset
  mlp3_kernel<2, 0><<<G1, 256, 0, stream>>>(fvbf, posf, hf1, H1,
      Wti + 3 * 16384, Wth + 3 * 16384, Wto + 3 * 4096,
      bif + 3 * DH, bhf + 3 * DH, bof + 3 * DF, fv1, nullptr, flag);
  finalize_odd_pos_kernel<<<(NE1 * 3 + 255) / 256, 256, 0, stream>>>(
      fv1, hf1, fvup2, d_out, 450000, flag, NE1, NV1);
}

// Round 10
// 596.967 us; speedup vs baseline: 1.1437x; 1.0573x over previous
//
#include <hip/hip_runtime.h>

#define NV0 30000
#define NE0 90000
#define H0 (2*NE0)      // 180000
#define NV1 (NV0+NE0)   // 120000
#define NE1 (3*NE0)     // 270000
#define H1 (2*NE1)      // 540000
#define DF 32
#define DH 128

typedef unsigned short bf16_t;
typedef unsigned int u32;
typedef __attribute__((ext_vector_type(8))) short short8;
typedef __attribute__((ext_vector_type(4))) float f32x4;

__device__ __forceinline__ float bf2f(bf16_t b) { return __uint_as_float(((u32)b) << 16); }
__device__ __forceinline__ bf16_t f2bf(float f) {
  u32 u = __float_as_uint(f);
  return (bf16_t)((u + 0x7fffu + ((u >> 16) & 1u)) >> 16);
}
__device__ __forceinline__ u32 pack2bf(float a, float b) {
  return (u32)f2bf(a) | ((u32)f2bf(b) << 16);
}
__device__ __forceinline__ float load_f(const void* p, long i, int isf32) {
  return isf32 ? ((const float*)p)[i] : bf2f(((const bf16_t*)p)[i]);
}
__device__ __forceinline__ void store_out(void* p, long i, float v, int isf32) {
  if (isf32) ((float*)p)[i] = v;
  else ((bf16_t*)p)[i] = f2bf(v);
}

// Compile-time ordering fence for cross-lane LDS RAW/WAR hazards within a wave.
// HW processes a wave's DS ops in issue order; we only need the COMPILER not to
// reorder ds_read/ds_write across this point.
__device__ __forceinline__ void lds_fence() {
  __builtin_amdgcn_fence(__ATOMIC_ACQ_REL, "wavefront");
  __builtin_amdgcn_sched_barrier(0);
}

struct F3 { float x, y, z; };
__device__ __forceinline__ F3 mkf3(float x, float y, float z){ F3 r; r.x=x; r.y=y; r.z=z; return r; }
__device__ __forceinline__ F3 f3sub(F3 a, F3 b){ return mkf3(a.x-b.x, a.y-b.y, a.z-b.z); }
__device__ __forceinline__ F3 f3add(F3 a, F3 b){ return mkf3(a.x+b.x, a.y+b.y, a.z+b.z); }
__device__ __forceinline__ float f3dot(F3 a, F3 b){ return a.x*b.x + a.y*b.y + a.z*b.z; }
__device__ __forceinline__ F3 f3crs(F3 a, F3 b){
  return mkf3(a.y*b.z - a.z*b.y, a.z*b.x - a.x*b.z, a.x*b.y - a.y*b.x);
}
__device__ __forceinline__ F3 f3nrm(F3 a){
  float r = rsqrtf(f3dot(a,a));
  return mkf3(a.x*r, a.y*r, a.z*r);
}

// ---- dtype detection
__global__ __launch_bounds__(256) void detect_kernel(const u32* __restrict__ fvw,
                                                     int* __restrict__ flag) {
  __shared__ int cnt;
  if (threadIdx.x == 0) cnt = 0;
  __syncthreads();
  int c = 0;
  #pragma unroll
  for (int j = 0; j < 2; ++j) {
    u32 w = fvw[threadIdx.x * 2 + j];
    u32 e = (w >> 7) & 0xffu;
    if (e > 140u) c++;
  }
  if (c) atomicAdd(&cnt, c);
  __syncthreads();
  if (threadIdx.x == 0) *flag = (cnt > 8) ? 1 : 0;
}

// biases: flagged dtype -> fp32
__global__ __launch_bounds__(256) void cvt_weights_kernel(const void* __restrict__ src,
                                                          float* __restrict__ dst, int n,
                                                          const int* __restrict__ flag) {
  int t = blockIdx.x * 256 + threadIdx.x;
  if (t >= n) return;
  dst[t] = load_f(src, t, *flag);
}

// Transposed bf16 weights for MFMA B-operand (layout [subnet][n][k], k contiguous).
__global__ __launch_bounds__(256) void pt_win_kernel(const void* __restrict__ W_in,
                                                     bf16_t* __restrict__ dst,
                                                     const int* __restrict__ flag) {
  int t = blockIdx.x * 256 + threadIdx.x;
  if (t >= 4 * DH * DH) return;
  int s = t >> 14, n = (t >> 7) & 127, k = t & 127;
  float v = (k >= 3) ? load_f(W_in, (long)s * (125 * DH) + (k - 3) * DH + n, *flag) : 0.f;
  dst[t] = f2bf(v);
}
__global__ __launch_bounds__(256) void pt_wh_kernel(const void* __restrict__ W_h,
                                                    bf16_t* __restrict__ dst,
                                                    const int* __restrict__ flag) {
  int t = blockIdx.x * 256 + threadIdx.x;
  if (t >= 4 * DH * DH) return;
  int s = t >> 14, n = (t >> 7) & 127, k = t & 127;
  dst[t] = f2bf(load_f(W_h, (long)s * (DH * DH) + k * DH + n, *flag));
}
__global__ __launch_bounds__(256) void pt_wo_kernel(const void* __restrict__ W_out,
                                                    bf16_t* __restrict__ dst,
                                                    const int* __restrict__ flag) {
  int t = blockIdx.x * 256 + threadIdx.x;
  if (t >= 4 * 32 * DH) return;
  int s = t >> 12, n = (t >> 7) & 31, k = t & 127;
  dst[t] = f2bf(load_f(W_out, (long)s * (DH * 32) + k * 32 + n, *flag));
}

// output 0: exact passthrough of fv positions
__global__ __launch_bounds__(256) void cvt_out0_kernel(const void* __restrict__ fv,
                                                       void* __restrict__ out,
                                                       const int* __restrict__ flag) {
  int t = blockIdx.x * 256 + threadIdx.x;
  if (t >= NV0 * 3) return;
  int v = t / 3, c = t - v * 3;
  if (*flag) ((float*)out)[t] = ((const float*)fv)[v * DF + c];
  else ((bf16_t*)out)[t] = ((const bf16_t*)fv)[v * DF + c];
}

#define XST 136   // LDS row stride (bf16 elems): 272B

__device__ __forceinline__ f32x4 mfma16(short8 a, short8 b, f32x4 c) {
  return __builtin_amdgcn_mfma_f32_16x16x32_bf16(a, b, c, 0, 0, 0);
}

// One 128->128 layer IN-PLACE, M=64 rows per wave (4 MFMA m-tiles share every
// W load -> 1.5KB W-traffic/flap instead of 3KB, and 4 independent MFMA chains
// hide each W-load wait). The wave loads its ENTIRE 64x128 source tile into
// af registers before any store -> in-place (no second LDS buffer).
__device__ __forceinline__ void mlp_layer4(
    short* buf,
    const bf16_t* __restrict__ Wt, const float* __restrict__ bias,
    int m0, int arow, int koff, int rrow)
{
  lds_fence();   // order af reads after previous phase's cross-lane LDS writes
  short8 af[4][4];
  #pragma unroll
  for (int mt = 0; mt < 4; ++mt)
    #pragma unroll
    for (int kq = 0; kq < 4; ++kq)
      af[mt][kq] = *(const short8*)(buf + (m0 + mt * 16 + arow) * XST + kq * 32 + koff);
  lds_fence();   // ALL tile reads issued before ANY in-place store (cross-lane WAR)
  #pragma unroll
  for (int ntl = 0; ntl < 8; ntl += 2) {
    f32x4 a0[4], a1[4];
    #pragma unroll
    for (int mt = 0; mt < 4; ++mt) { a0[mt] = {0.f,0.f,0.f,0.f}; a1[mt] = {0.f,0.f,0.f,0.f}; }
    #pragma unroll
    for (int kq = 0; kq < 4; ++kq) {
      short8 w0 = *(const short8*)(Wt + (ntl * 16 + arow) * DH + kq * 32 + koff);
      short8 w1 = *(const short8*)(Wt + ((ntl + 1) * 16 + arow) * DH + kq * 32 + koff);
      #pragma unroll
      for (int mt = 0; mt < 4; ++mt) {
        a0[mt] = mfma16(af[mt][kq], w0, a0[mt]);
        a1[mt] = mfma16(af[mt][kq], w1, a1[mt]);
      }
    }
    int c0 = ntl * 16 + arow, c1 = c0 + 16;
    float bb0 = bias[c0], bb1 = bias[c1];
    #pragma unroll
    for (int mt = 0; mt < 4; ++mt) {
      #pragma unroll
      for (int r = 0; r < 4; ++r) {
        int rm = m0 + mt * 16 + rrow + r;
        buf[rm * XST + c0] = (short)f2bf(fmaxf(a0[mt][r] + bb0, 0.f));
        buf[rm * XST + c1] = (short)f2bf(fmaxf(a1[mt][r] + bb1, 0.f));
      }
    }
  }
  lds_fence();   // order this layer's writes before next phase's reads
}

// Fused per-pass kernel. 128 flaps/block = 2 waves x M=64 (wave wv owns rows
// [64wv, 64wv+64) end-to-end — strictly wave-local, barrier-free).
// IN-PLACE layers: single X buffer -> LDS ~40KB -> 4 blocks/CU (8 waves/CU);
// occupancy traded for 2x W-amortization + 4-chain MFMA ILP per W load.
// RAW=1: gather raw input. RAW=0: gather 64B bf16 mirror rows + exact f32
// positions from the L2-resident posf array (frame math exact — no bf16 NaN).
template<int MODE, int RAW>
__global__ __launch_bounds__(128, 2) void mlp3_kernel(
    const void* __restrict__ fvin, const float* __restrict__ posf,
    const int* __restrict__ hfIdx, int nH,
    const bf16_t* __restrict__ Wt1, const bf16_t* __restrict__ Wt2,
    const bf16_t* __restrict__ Wt3,
    const float* __restrict__ b1, const float* __restrict__ b2,
    const float* __restrict__ b3,
    float* __restrict__ outp, float* __restrict__ dofp,
    const int* __restrict__ flag)
{
  __shared__ __align__(16) short Xl[128 * XST];  // X tile; later H; later Y (fp32, stride 68, row-own)
  __shared__ float LFl[128 * 9];
  __shared__ int   idxl[128];                    // center vertex per flap

  const int t = threadIdx.x;
  const int lane = t & 63;
  const int m0 = (t >> 6) * 64;
  const int arow = lane & 15;
  const int koff = (lane >> 4) * 8;
  const int rrow = (lane >> 4) * 4;
  const int isf32 = RAW ? *flag : 0;

  // bijective XCD-chunked swizzle: blocks on one XCD get a contiguous flap range
  const int nwg = gridDim.x;
  const int q = nwg >> 3, r = nwg & 7;
  const int xcd = blockIdx.x & 7;
  const int loc = blockIdx.x >> 3;
  const int bswz = (xcd < r ? xcd * (q + 1) : r * (q + 1) + (xcd - r) * q) + loc;
  const long h0 = (long)bswz * 128;

  // ---- phase 1: gather + in-register frame, wave-local (lane -> 4 flaps, vertex lane&3)
  #pragma unroll
  for (int half = 0; half < 4; ++half) {
    const int m = m0 + half * 16 + (lane >> 2);
    const int v = lane & 3;
    const long h = h0 + m;
    int vid = (h < nH) ? hfIdx[h * 4 + v] : 0;
    if (v == 0) idxl[m] = vid;
    float px, py, pz;
    u32 w[16];
    if (RAW) {
      if (!isf32) {
        const uint4* src = (const uint4*)((const bf16_t*)fvin + (size_t)vid * DF);
        #pragma unroll
        for (int j = 0; j < 4; ++j) {
          uint4 x = src[j];
          w[j * 4 + 0] = x.x; w[j * 4 + 1] = x.y;
          w[j * 4 + 2] = x.z; w[j * 4 + 3] = x.w;
        }
        px = bf2f((bf16_t)(w[0] & 0xffff));
        py = bf2f((bf16_t)(w[0] >> 16));
        pz = bf2f((bf16_t)(w[1] & 0xffff));
      } else {
        const float4* src = (const float4*)((const float*)fvin + (size_t)vid * DF);
        float4 x0 = src[0];
        px = x0.x; py = x0.y; pz = x0.z;
        w[0] = pack2bf(x0.x, x0.y); w[1] = pack2bf(x0.z, x0.w);
        #pragma unroll
        for (int j = 1; j < 8; ++j) {
          float4 x = src[j];
          w[j * 2 + 0] = pack2bf(x.x, x.y);
          w[j * 2 + 1] = pack2bf(x.z, x.w);
        }
      }
    } else {
      // bf16 mirror row (channel values identical to f2bf of the f32 source)
      const uint4* src = (const uint4*)((const bf16_t*)fvin + (size_t)vid * DF);
      #pragma unroll
      for (int j = 0; j < 4; ++j) {
        uint4 x = src[j];
        w[j * 4 + 0] = x.x; w[j * 4 + 1] = x.y;
        w[j * 4 + 2] = x.z; w[j * 4 + 3] = x.w;
      }
      // exact f32 positions from the L2-resident side array
      px = posf[(size_t)vid * 3 + 0];
      py = posf[(size_t)vid * 3 + 1];
      pz = posf[(size_t)vid * 3 + 2];
    }
    // local frame via 4-lane-group shuffles (redundant on all 4 lanes; cheap)
    const int bl = lane & ~3;
    F3 p0 = mkf3(__shfl(px, bl),     __shfl(py, bl),     __shfl(pz, bl));
    F3 p1 = mkf3(__shfl(px, bl | 1), __shfl(py, bl | 1), __shfl(pz, bl | 1));
    F3 p2 = mkf3(__shfl(px, bl | 2), __shfl(py, bl | 2), __shfl(pz, bl | 2));
    F3 p3 = mkf3(__shfl(px, bl | 3), __shfl(py, bl | 3), __shfl(pz, bl | 3));
    F3 e1  = f3sub(p1, p0);
    F3 B1  = f3nrm(e1);
    F3 fn0 = f3nrm(f3crs(e1, f3sub(p2, p0)));
    F3 fn1 = f3nrm(f3crs(f3sub(p0, p1), f3sub(p3, p1)));
    F3 B3  = f3nrm(f3add(fn0, fn1));
    F3 B2  = f3crs(B3, B1);
    if (v == 0) {
      float* lf = LFl + m * 9;
      lf[0] = B1.x; lf[1] = B1.y; lf[2] = B1.z;
      lf[3] = B2.x; lf[4] = B2.y; lf[5] = B2.z;
      lf[6] = B3.x; lf[7] = B3.y; lf[8] = B3.z;
      // v0 pos channels (k 0..2) hit zero rows of Wt1 -> keep raw, no need to clear
    } else {
      // channels v*32 + {0,1,2} = local coords of (p_v - p0); channel v*32+3 kept original
      F3 d = f3sub(mkf3(px, py, pz), p0);
      w[0] = pack2bf(f3dot(d, B1), f3dot(d, B2));
      w[1] = (w[1] & 0xffff0000u) | (u32)f2bf(f3dot(d, B3));
    }
    uint4* xrow = (uint4*)(Xl + m * XST + v * 32);   // 272B row stride: 16B-aligned
    #pragma unroll
    for (int j = 0; j < 4; ++j)
      xrow[j] = make_uint4(w[j * 4 + 0], w[j * 4 + 1], w[j * 4 + 2], w[j * 4 + 3]);
  }

  // ======== LAYER 1 / LAYER 2 (wave-local, in-place; fenced inside) ========
  mlp_layer4(Xl, Wt1, b1, m0, arow, koff, rrow);
  mlp_layer4(Xl, Wt2, b2, m0, arow, koff, rrow);

  // ======== LAYER 3: Y = H2 @ W3 + b3 (N=32, no relu); Y fp32 into row-own Xl storage ========
  {
    lds_fence();   // order af reads after layer-2's cross-lane Xl writes
    short8 af[4][4];
    #pragma unroll
    for (int mt = 0; mt < 4; ++mt)
      #pragma unroll
      for (int kq = 0; kq < 4; ++kq)
        af[mt][kq] = *(const short8*)(Xl + (m0 + mt * 16 + arow) * XST + kq * 32 + koff);
    f32x4 a0[4], a1[4];
    #pragma unroll
    for (int mt = 0; mt < 4; ++mt) { a0[mt] = {0.f,0.f,0.f,0.f}; a1[mt] = {0.f,0.f,0.f,0.f}; }
    #pragma unroll
    for (int kq = 0; kq < 4; ++kq) {
      short8 w0 = *(const short8*)(Wt3 + arow * DH + kq * 32 + koff);
      short8 w1 = *(const short8*)(Wt3 + (16 + arow) * DH + kq * 32 + koff);
      #pragma unroll
      for (int mt = 0; mt < 4; ++mt) {
        a0[mt] = mfma16(af[mt][kq], w0, a0[mt]);
        a1[mt] = mfma16(af[mt][kq], w1, a1[mt]);
      }
    }
    lds_fence();   // af reads ordered before aliasing Yf writes
    float* Yf = (float*)Xl;
    float bb0 = b3[arow], bb1 = b3[16 + arow];
    #pragma unroll
    for (int mt = 0; mt < 4; ++mt) {
      #pragma unroll
      for (int r = 0; r < 4; ++r) {
        int rm = m0 + mt * 16 + rrow + r;
        Yf[rm * 68 + arow]      = a0[mt][r] + bb0;   // row rm's Y lives in row rm's Xl bytes
        Yf[rm * 68 + 16 + arow] = a1[mt][r] + bb1;
      }
    }
  }
  lds_fence();     // Yf writes ordered before epilogue's cross-lane reads

  // ======== epilogue: local2global + pool (wave-own 64 rows) ========
  float* Yf = (float*)Xl;
  #pragma unroll
  for (int i = 0; i < 32; ++i) {
    int row = m0 + i * 2 + (lane >> 5);
    long h = h0 + row;
    int ch = lane & 31;
    float val = 0.f;
    if (h < nH) {
      val = Yf[row * 68 + ch];
      if (ch < 3) {
        float y0 = Yf[row * 68 + 0], y1 = Yf[row * 68 + 1], y2 = Yf[row * 68 + 2];
        val = y0 * LFl[row * 9 + ch] + y1 * LFl[row * 9 + 3 + ch] + y2 * LFl[row * 9 + 6 + ch];
      }
    }
    if (MODE == 0) {
      if (h < nH) {
        atomicAdd(&outp[(size_t)idxl[row] * DF + ch], val);
        if (ch == 0) atomicAdd(&dofp[idxl[row]], 1.f);
      }
    } else {
      // half-edge pair (2e,2e+1) sits on lanes l / l+32 of this iteration:
      // combine in-wave -> plain store, no atomics, no zero-init of the odd buffer.
      float sum = val + __shfl_xor(val, 32);
      if (h < nH && lane < 32) {
        if (MODE == 1) outp[(size_t)(h >> 1) * DF + ch] = 0.5f * sum;
        else if (ch < 3) outp[(size_t)(h >> 1) * 3 + ch] = 0.5f * sum;
      }
    }
  }
}

// ---- finalize kernels (also emit the bf16 channel mirror + f32 pos array) ----
template<int RAW>
__global__ __launch_bounds__(256) void finalize_even_kernel(
    float* buf, const float* __restrict__ dof,
    const void* __restrict__ prevraw, const float* __restrict__ prevf,
    void* __restrict__ out, int outbase, const int* __restrict__ flag, int nV,
    bf16_t* __restrict__ mirror, float* __restrict__ posf) {
  int t = blockIdx.x * 256 + threadIdx.x;
  if (t >= nV * DF) return;
  int v = t >> 5, c = t & 31;
  float val = buf[t] / fmaxf(dof[v], 1.0f);
  if (c < 3) {
    float pp = RAW ? load_f(prevraw, (long)v * DF + c, *flag) : prevf[(long)v * DF + c];
    val += pp;
    store_out(out, (long)outbase + (long)v * 3 + c, val, *flag);
    posf[(size_t)v * 3 + c] = val;
  }
  buf[t] = val;
  mirror[t] = f2bf(val);
}

__global__ __launch_bounds__(256) void finalize_odd_full_kernel(
    float* oddbuf, const int* __restrict__ hfIdx,
    const float* fveven, void* __restrict__ out, int outbase,
    const int* __restrict__ flag, int nE, int nVeven,
    bf16_t* __restrict__ mirror_off, float* __restrict__ posf_off) {
  int t = blockIdx.x * 256 + threadIdx.x;
  if (t >= nE * DF) return;
  int e = t >> 5, c = t & 31;
  float val = oddbuf[t];
  if (c < 3) {
    int a0 = hfIdx[(size_t)(2 * e) * 4 + 0];
    int a1 = hfIdx[(size_t)(2 * e) * 4 + 1];
    int b0 = hfIdx[(size_t)(2 * e + 1) * 4 + 0];
    int b1 = hfIdx[(size_t)(2 * e + 1) * 4 + 1];
    val += 0.25f * (fveven[(size_t)a0 * DF + c] + fveven[(size_t)a1 * DF + c] +
                    fveven[(size_t)b0 * DF + c] + fveven[(size_t)b1 * DF + c]);
    store_out(out, (long)outbase + (long)(nVeven + e) * 3 + c, val, *flag);
    posf_off[(size_t)e * 3 + c] = val;
  }
  oddbuf[t] = val;
  mirror_off[t] = f2bf(val);
}

__global__ __launch_bounds__(256) void finalize_odd_pos_kernel(
    const float* __restrict__ odd3, const int* __restrict__ hfIdx,
    const float* __restrict__ fveven, void* __restrict__ out, int outbase,
    const int* __restrict__ flag, int nE, int nVeven) {
  int t = blockIdx.x * 256 + threadIdx.x;
  if (t >= nE * 3) return;
  int e = t / 3, c = t - e * 3;
  int a0 = hfIdx[(size_t)(2 * e) * 4 + 0];
  int a1 = hfIdx[(size_t)(2 * e) * 4 + 1];
  int b0 = hfIdx[(size_t)(2 * e + 1) * 4 + 0];
  int b1 = hfIdx[(size_t)(2 * e + 1) * 4 + 1];
  float val = odd3[t] + 0.25f * (fveven[(size_t)a0 * DF + c] + fveven[(size_t)a1 * DF + c] +
                                 fveven[(size_t)b0 * DF + c] + fveven[(size_t)b1 * DF + c]);
  store_out(out, (long)outbase + (long)(nVeven + e) * 3 + c, val, *flag);
}

extern "C" void kernel_launch(void* const* d_in, const int* in_sizes, int n_in,
                              void* d_out, int out_size, void* d_ws, size_t ws_size,
                              hipStream_t stream) {
  const void* fv    = d_in[0];
  const void* W_in  = d_in[1];
  const void* b_in  = d_in[2];
  const void* W_h   = d_in[3];
  const void* b_h   = d_in[4];
  const void* W_out = d_in[5];
  const void* b_out = d_in[6];
  const int* hf0 = (const int*)d_in[7];
  const int* hf1 = (const int*)d_in[8];
  (void)in_sizes; (void)n_in; (void)out_size;

  // workspace (~38.7 MiB)
  float* fv1   = (float*)d_ws;            // 3,840,000 (120000x32)
  float* fvup2 = fv1   + 3840000;         // 3,840,000
  float* dof   = fvup2 + 3840000;         // 120,000
  float* bif   = dof   + 120000;          // 512
  float* bhf   = bif   + 512;             // 512
  float* bof   = bhf   + 512;             // 128
  int*   flag  = (int*)(bof + 128);       // 4 ints (1 used)
  bf16_t* Wti  = (bf16_t*)(flag + 4);     // 4x128x128
  bf16_t* Wth  = Wti + 65536;             // 4x128x128
  bf16_t* Wto  = Wth + 65536;             // 4x32x128
  bf16_t* fvbf = Wto + 16384;             // 120000x32 bf16 channel mirror (7.68 MB)
  float* posf  = (float*)(fvbf + 3840000); // 120000x3 f32 positions (1.44 MB, L2-resident)
  const size_t needed = ((size_t)3840000 * 2 + 120000 + 512 * 2 + 128 + 4) * 4
                      + (65536 * 2 + 16384) * 2 + (size_t)3840000 * 2
                      + (size_t)360000 * 4;
  if (ws_size < needed) return;

  float* odd_acc0 = fv1 + (size_t)NV0 * DF;  // level-0 odd region (90000x32)

  // ---- dtype detect + weight staging
  detect_kernel<<<1, 256, 0, stream>>>((const u32*)fv, flag);
  pt_win_kernel<<<256, 256, 0, stream>>>(W_in, Wti, flag);
  pt_wh_kernel<<<256, 256, 0, stream>>>(W_h, Wth, flag);
  pt_wo_kernel<<<64, 256, 0, stream>>>(W_out, Wto, flag);
  cvt_weights_kernel<<<2, 256, 0, stream>>>(b_in, bif, 512, flag);
  cvt_weights_kernel<<<2, 256, 0, stream>>>(b_h, bhf, 512, flag);
  cvt_weights_kernel<<<1, 256, 0, stream>>>(b_out, bof, 128, flag);
  cvt_out0_kernel<<<(NV0 * 3 + 255) / 256, 256, 0, stream>>>(fv, d_out, flag);

  const int G0 = (H0 + 127) / 128, G1 = (H1 + 127) / 128;

  // ================= level 0 =================
  hipMemsetAsync(fv1, 0, (size_t)NV0 * DF * 4, stream);
  hipMemsetAsync(dof, 0, (size_t)NV0 * 4, stream);
  mlp3_kernel<0, 1><<<G0, 128, 0, stream>>>(fv, nullptr, hf0, H0,
      Wti + 0 * 16384, Wth + 0 * 16384, Wto + 0 * 4096,
      bif + 0 * DH, bhf + 0 * DH, bof + 0 * DF, fv1, dof, flag);
  finalize_even_kernel<1><<<(NV0 * DF + 255) / 256, 256, 0, stream>>>(
      fv1, dof, fv, nullptr, d_out, 90000, flag, NV0, fvbf, posf);
  // odd pass gathers mirror channels + posf positions (rows 0..NV0 ready);
  // fully overwrites odd_acc0 (pair-combined plain stores) -> no memset
  mlp3_kernel<1, 0><<<G0, 128, 0, stream>>>(fvbf, posf, hf0, H0,
      Wti + 1 * 16384, Wth + 1 * 16384, Wto + 1 * 4096,
      bif + 1 * DH, bhf + 1 * DH, bof + 1 * DF, odd_acc0, nullptr, flag);
  finalize_odd_full_kernel<<<(NE0 * DF + 255) / 256, 256, 0, stream>>>(
      odd_acc0, hf0, fv1, d_out, 90000, flag, NE0, NV0,
      fvbf + (size_t)NV0 * DF, posf + (size_t)NV0 * 3);

  // ================= level 1 =================
  hipMemsetAsync(fvup2, 0, (size_t)NV1 * DF * 4, stream);
  hipMemsetAsync(dof, 0, (size_t)NV1 * 4, stream);
  // even pass gathers mirror+posf (rows 0..NV1 complete: even + odd finalize)
  mlp3_kernel<0, 0><<<G1, 128, 0, stream>>>(fvbf, posf, hf1, H1,
      Wti + 2 * 16384, Wth + 2 * 16384, Wto + 2 * 4096,
      bif + 2 * DH, bhf + 2 * DH, bof + 2 * DF, fvup2, dof, flag);
  // re-targets mirror+posf to fvup2 values (rows 0..NV1)
  finalize_even_kernel<0><<<(NV1 * DF + 255) / 256, 256, 0, stream>>>(
      fvup2, dof, nullptr, fv1, d_out, 450000, flag, NV1, fvbf, posf);
  // odd3 region fully overwritten by MODE 2 stores -> no memset
  mlp3_kernel<2, 0><<<G1, 128, 0, stream>>>(fvbf, posf, hf1, H1,
      Wti + 3 * 16384, Wth + 3 * 16384, Wto + 3 * 4096,
      bif + 3 * DH, bhf + 3 * DH, bof + 3 * DF, fv1, nullptr, flag);
  finalize_odd_pos_kernel<<<(NE1 * 3 + 255) / 256, 256, 0, stream>>>(
      fv1, hf1, fvup2, d_out, 450000, flag, NE1, NV1);
}